// Round 1
// baseline (2723.587 us; speedup 1.0000x reference)
//
#include <hip/hip_runtime.h>
#include <math.h>

#define BSZ 4
#define VN 2048
#define SS 7
#define KNB 10

// ---------------------------------------------------------------- utilities

__global__ void norm_dirs_kernel(const float* __restrict__ d, float* __restrict__ sd, int C) {
    int c = blockIdx.x * blockDim.x + threadIdx.x;
    if (c >= C) return;
    float a = d[c], b = d[C + c], e = d[2 * C + c];
    float nrm = sqrtf(a * a + b * b + e * e);
    float den = fmaxf(nrm, 1e-12f);
    sd[c] = a / den; sd[C + c] = b / den; sd[2 * C + c] = e / den;
}

// (O, Cin) row-major -> (Cin, O) row-major
__global__ void transpose_kernel(const float* __restrict__ w, float* __restrict__ wt, int O, int Cin) {
    long i = blockIdx.x * 256L + threadIdx.x;
    if (i >= (long)O * Cin) return;
    int o = (int)(i / Cin), c = (int)(i % Cin);
    wt[(long)c * O + o] = w[i];
}

// ---------------------------------------------------------------- knn
// K nearest neighbors (excluding self) among first Nsrc vertices, for first T targets.
template <int KK>
__global__ void knn_kernel(const float* __restrict__ verts, int Nsrc, int T, int* __restrict__ out) {
    int t = blockIdx.x * blockDim.x + threadIdx.x;
    if (t >= BSZ * T) return;
    int b = t / T, i = t % T;
    const float* vb = verts + (long)b * VN * 3;
    float px = vb[i * 3], py = vb[i * 3 + 1], pz = vb[i * 3 + 2];
    float d[KK]; int id[KK];
#pragma unroll
    for (int q = 0; q < KK; q++) { d[q] = 1e30f; id[q] = 0; }
    for (int j = 0; j < Nsrc; j++) {
        if (j == i) continue;
        float dx = vb[j * 3] - px, dy = vb[j * 3 + 1] - py, dz = vb[j * 3 + 2] - pz;
        float dd = dx * dx + dy * dy + dz * dz;
        if (dd < d[KK - 1]) {
            int jj = j;
#pragma unroll
            for (int q = 0; q < KK; q++) {
                if (dd < d[q]) {
                    float td = d[q]; d[q] = dd; dd = td;
                    int ti = id[q]; id[q] = jj; jj = ti;
                }
            }
        }
    }
#pragma unroll
    for (int q = 0; q < KK; q++) out[(long)t * KK + q] = id[q];
}

// ---------------------------------------------------------------- conv_surface
// fm0[b][v][c] = sum_s max(0, max_n nd_n . sd[:, s*128+c]);  block=(b,v), 128 threads
__global__ void conv_surface_kernel(const float* __restrict__ verts, const int* __restrict__ nb,
                                    const float* __restrict__ sd, float* __restrict__ fm0) {
    int bv = blockIdx.x;
    int b = bv / VN, v = bv % VN;
    __shared__ float snd[KNB][3];
    int tid = threadIdx.x;
    if (tid < KNB) {
        int nj = nb[(long)bv * KNB + tid];
        const float* vb = verts + (long)b * VN * 3;
        float dx = vb[nj * 3] - vb[v * 3];
        float dy = vb[nj * 3 + 1] - vb[v * 3 + 1];
        float dz = vb[nj * 3 + 2] - vb[v * 3 + 2];
        float den = fmaxf(sqrtf(dx * dx + dy * dy + dz * dz), 1e-12f);
        snd[tid][0] = dx / den; snd[tid][1] = dy / den; snd[tid][2] = dz / den;
    }
    __syncthreads();
    int c = tid;
    float acc = 0.f;
    for (int s = 0; s < SS; s++) {
        int col = s * 128 + c;
        float s0 = sd[col], s1 = sd[896 + col], s2 = sd[2 * 896 + col];
        float m = 0.f;
#pragma unroll
        for (int n = 0; n < KNB; n++) {
            float dot = snd[n][0] * s0 + snd[n][1] * s1 + snd[n][2] * s2;
            m = fmaxf(m, dot);
        }
        acc += m;
    }
    fm0[(long)bv * 128 + c] = acc;
}

// ---------------------------------------------------------------- conv_layer act
// out[b][v][c] = fo[bv][c] + sum_s max_n relu(nd_n . sd[:,s*outC+c]) * fo[nb_n][outC + s*outC + c]
// block=(b,v), blockDim = outC
__global__ void conv_act_kernel(const float* __restrict__ verts, const int* __restrict__ nb,
                                const float* __restrict__ sd, const float* __restrict__ fo,
                                float* __restrict__ out, int Vl, int outC) {
    int bv = blockIdx.x;
    int b = bv / Vl, v = bv % Vl;
    __shared__ float snd[KNB][3];
    __shared__ int srow[KNB];
    int tid = threadIdx.x;
    if (tid < KNB) {
        int nj = nb[(long)bv * KNB + tid];
        srow[tid] = b * Vl + nj;
        const float* vb = verts + (long)b * VN * 3;
        float dx = vb[nj * 3] - vb[v * 3];
        float dy = vb[nj * 3 + 1] - vb[v * 3 + 1];
        float dz = vb[nj * 3 + 2] - vb[v * 3 + 2];
        float den = fmaxf(sqrtf(dx * dx + dy * dy + dz * dz), 1e-12f);
        snd[tid][0] = dx / den; snd[tid][1] = dy / den; snd[tid][2] = dz / den;
    }
    __syncthreads();
    int c = tid;
    int SC = SS * outC;
    int foN = SC + outC;
    float acc = fo[(long)bv * foN + c];  // center
    for (int s = 0; s < SS; s++) {
        int col = s * outC + c;
        float s0 = sd[col], s1 = sd[SC + col], s2 = sd[2 * SC + col];
        float m = -1e30f;
#pragma unroll
        for (int n = 0; n < KNB; n++) {
            float dot = snd[n][0] * s0 + snd[n][1] * s1 + snd[n][2] * s2;
            float th = fmaxf(dot, 0.f);
            float sup = fo[(long)srow[n] * foN + outC + col];
            m = fmaxf(m, th * sup);
        }
        acc += m;
    }
    out[(long)bv * outC + c] = acc;
}

// ---------------------------------------------------------------- batchnorm
__global__ void bn_stat_kernel(const float* __restrict__ x, float* __restrict__ stat, int R, int C) {
    int c = threadIdx.x;
    int chunk = (R + gridDim.x - 1) / gridDim.x;
    int r0 = blockIdx.x * chunk;
    int r1 = min(r0 + chunk, R);
    float s = 0.f, s2 = 0.f;
    for (int r = r0; r < r1; r++) {
        float v = x[(long)r * C + c];
        s += v; s2 += v * v;
    }
    atomicAdd(&stat[c], s);
    atomicAdd(&stat[C + c], s2);
}

__global__ void bn_apply_relu_kernel(const float* __restrict__ x, const float* __restrict__ stat,
                                     const float* __restrict__ g, const float* __restrict__ be,
                                     float* __restrict__ out, int R, int C) {
    long i = blockIdx.x * 256L + threadIdx.x;
    if (i >= (long)R * C) return;
    int c = (int)(i % C);
    float mu = stat[c] / R;
    float var = stat[C + c] / R - mu * mu;
    var = fmaxf(var, 0.f);
    float y = (x[i] - mu) * rsqrtf(var + 1e-5f) * g[c] + be[c];
    out[i] = fmaxf(y, 0.f);
}

// ---------------------------------------------------------------- pool (max over 4 nbrs)
__global__ void pool_kernel(const float* __restrict__ fm, const int* __restrict__ idx,
                            float* __restrict__ out, int Vin, int T, int C) {
    long i = blockIdx.x * 256L + threadIdx.x;
    if (i >= (long)BSZ * T * C) return;
    int c = (int)(i % C);
    long bt = i / C;
    int b = (int)(bt / T), t = (int)(bt % T);
    const int* id = idx + ((long)b * T + t) * 4;
    float m = -1e30f;
#pragma unroll
    for (int n = 0; n < 4; n++)
        m = fmaxf(m, fm[((long)b * Vin + id[n]) * C + c]);
    out[i] = m;
}

// ---------------------------------------------------------------- GEMM  C = A(M,K) @ B(K,N) + bias, opt relu
__global__ __launch_bounds__(256) void gemm_kernel(const float* __restrict__ A, const float* __restrict__ B,
                                                   const float* __restrict__ bias, float* __restrict__ C,
                                                   int M, int K, int N, int do_relu) {
    __shared__ float As[16][68];
    __shared__ float Bs[16][68];
    int tid = threadIdx.x;
    int tx = tid % 16, ty = tid / 16;
    int m0 = blockIdx.y * 64, n0 = blockIdx.x * 64;
    float acc[4][4] = {};
    int aRow = tid / 4;
    int aK = (tid % 4) * 4;
    int bK = tid / 16;
    int bN = (tid % 16) * 4;
    bool nfull = (n0 + 64 <= N) && ((N & 3) == 0);
    for (int k0 = 0; k0 < K; k0 += 16) {
        float4 av = *(const float4*)(A + (long)(m0 + aRow) * K + k0 + aK);
        As[aK + 0][aRow] = av.x; As[aK + 1][aRow] = av.y;
        As[aK + 2][aRow] = av.z; As[aK + 3][aRow] = av.w;
        if (nfull) {
            float4 bv = *(const float4*)(B + (long)(k0 + bK) * N + n0 + bN);
            Bs[bK][bN] = bv.x; Bs[bK][bN + 1] = bv.y; Bs[bK][bN + 2] = bv.z; Bs[bK][bN + 3] = bv.w;
        } else {
#pragma unroll
            for (int j = 0; j < 4; j++) {
                int n = n0 + bN + j;
                Bs[bK][bN + j] = (n < N) ? B[(long)(k0 + bK) * N + n] : 0.f;
            }
        }
        __syncthreads();
#pragma unroll
        for (int kk = 0; kk < 16; kk++) {
            float4 a4 = *(const float4*)&As[kk][ty * 4];
            float4 b4 = *(const float4*)&Bs[kk][tx * 4];
            float a[4] = {a4.x, a4.y, a4.z, a4.w};
            float bb[4] = {b4.x, b4.y, b4.z, b4.w};
#pragma unroll
            for (int ii = 0; ii < 4; ii++)
#pragma unroll
                for (int jj = 0; jj < 4; jj++)
                    acc[ii][jj] += a[ii] * bb[jj];
        }
        __syncthreads();
    }
#pragma unroll
    for (int ii = 0; ii < 4; ii++) {
        int m = m0 + ty * 4 + ii;
#pragma unroll
        for (int jj = 0; jj < 4; jj++) {
            int n = n0 + tx * 4 + jj;
            if (n < N) {
                float v = acc[ii][jj] + bias[n];
                if (do_relu) v = fmaxf(v, 0.f);
                C[(long)m * N + n] = v;
            }
        }
    }
}

// ---------------------------------------------------------------- global max over 128 rows
__global__ void fglob_kernel(const float* __restrict__ fm4, float* __restrict__ fg) {
    int t = blockIdx.x * blockDim.x + threadIdx.x;
    if (t >= BSZ * 512) return;
    int b = t / 512, c = t % 512;
    float m = -1e30f;
    for (int r = 0; r < 128; r++)
        m = fmaxf(m, fm4[((long)b * 128 + r) * 512 + c]);
    fg[t] = m;
}

// ---------------------------------------------------------------- nearest source index
__global__ void nearest_kernel(const float* __restrict__ verts, int SN, int* __restrict__ out) {
    int t = blockIdx.x * blockDim.x + threadIdx.x;
    if (t >= BSZ * VN) return;
    int b = t / VN, i = t % VN;
    const float* vb = verts + (long)b * VN * 3;
    float px = vb[i * 3], py = vb[i * 3 + 1], pz = vb[i * 3 + 2];
    float best = 1e30f; int bi = 0;
    for (int j = 0; j < SN; j++) {
        float dx = vb[j * 3] - px, dy = vb[j * 3 + 1] - py, dz = vb[j * 3 + 2] - pz;
        float dd = dx * dx + dy * dy + dz * dz;
        if (dd < best) { best = dd; bi = j; }
    }
    out[t] = bi;
}

// ---------------------------------------------------------------- fuse assembly
__global__ void fuse_kernel(const float* __restrict__ fm0, const float* __restrict__ fm1,
                            const float* __restrict__ fm2, const float* __restrict__ fm3,
                            const float* __restrict__ fm4, const float* __restrict__ fg,
                            const float* __restrict__ onehot,
                            const int* __restrict__ n1, const int* __restrict__ n2,
                            float* __restrict__ fuse) {
    long i = blockIdx.x * 256L + threadIdx.x;
    if (i >= 8192L * 1808) return;
    int c = (int)(i % 1808);
    long row = i / 1808;
    int b = (int)(row / VN);
    float val;
    if (c < 128)       val = fm0[row * 128 + c];
    else if (c < 256)  val = fm1[row * 128 + (c - 128)];
    else if (c < 512)  val = fm2[((long)b * 512 + n1[row]) * 256 + (c - 256)];
    else if (c < 768)  val = fm3[((long)b * 512 + n1[row]) * 256 + (c - 512)];
    else if (c < 1280) val = fm4[((long)b * 128 + n2[row]) * 512 + (c - 768)];
    else if (c < 1792) val = fg[b * 512 + (c - 1280)];
    else               val = onehot[b * 16 + (c - 1792)];
    fuse[i] = val;
}

__global__ void feat_kernel(const float* __restrict__ fuse, float* __restrict__ feat) {
    long i = blockIdx.x * 256L + threadIdx.x;
    if (i >= 8192L * 1296) return;
    int cf = (int)(i % 1296);
    long row = i / 1296;
    int c = (cf < 1280) ? cf : cf + 512;  // skip fg block
    feat[i] = fuse[row * 1808 + c];
}

__global__ void pred_scatter_kernel(const float* __restrict__ pred, float* __restrict__ out) {
    long i = blockIdx.x * 256L + threadIdx.x;
    if (i >= 8192L * 30) return;
    int c = (int)(i % 30);
    long row = i / 30;
    float v = pred[i];
    if (c < 6) out[row * 6 + c] = v;
    else       out[49152 + row * 24 + (c - 6)] = v;
}

// ---------------------------------------------------------------- launch

extern "C" void kernel_launch(void* const* d_in, const int* in_sizes, int n_in,
                              void* d_out, int out_size, void* d_ws, size_t ws_size,
                              hipStream_t stream) {
    const float* verts  = (const float*)d_in[0];
    const float* onehot = (const float*)d_in[1];
    const float* dir0 = (const float*)d_in[2];
    const float* w1 = (const float*)d_in[3];
    const float* b1 = (const float*)d_in[4];
    const float* dir1 = (const float*)d_in[5];
    const float* w2 = (const float*)d_in[6];
    const float* b2 = (const float*)d_in[7];
    const float* dir2 = (const float*)d_in[8];
    const float* w3 = (const float*)d_in[9];
    const float* b3 = (const float*)d_in[10];
    const float* dir3 = (const float*)d_in[11];
    const float* w4 = (const float*)d_in[12];
    const float* b4 = (const float*)d_in[13];
    const float* dir4 = (const float*)d_in[14];
    const float* g_bn1 = (const float*)d_in[15];
    const float* be_bn1 = (const float*)d_in[16];
    const float* g_bn2 = (const float*)d_in[17];
    const float* be_bn2 = (const float*)d_in[18];
    const float* g_bn3 = (const float*)d_in[19];
    const float* be_bn3 = (const float*)d_in[20];
    const float* wc1 = (const float*)d_in[21];
    const float* bc1 = (const float*)d_in[22];
    const float* wc2 = (const float*)d_in[23];
    const float* bc2 = (const float*)d_in[24];
    const float* wc3 = (const float*)d_in[25];
    const float* bc3 = (const float*)d_in[26];
    float* outf = (float*)d_out;

    // bump allocator over workspace (float units, 64B aligned)
    float* wsf = (float*)d_ws;
    size_t off = 0;
    auto alloc = [&](size_t n) { float* p = wsf + off; off += (n + 15) & ~(size_t)15; return p; };

    float* sd0 = alloc(3 * 896);
    float* sd1 = alloc(3 * 896);
    float* sd2 = alloc(3 * 1792);
    float* sd3 = alloc(3 * 1792);
    float* sd4 = alloc(3 * 3584);
    float* wc1t = alloc(1808L * 512);
    float* wc2t = alloc(512L * 512);
    float* wc3t = alloc(512L * 30);
    float* fm0 = alloc(8192L * 128);
    float* fm1 = alloc(8192L * 128);
    float* c1  = alloc(8192L * 128);
    float* fp1 = alloc(2048L * 128);
    float* fm2 = alloc(2048L * 256);
    float* c2  = alloc(2048L * 256);
    float* fm3 = alloc(2048L * 256);
    float* c3  = alloc(2048L * 256);
    float* fp2 = alloc(512L * 256);
    float* fm4 = alloc(512L * 512);
    float* fg  = alloc(BSZ * 512);
    float* fbuf = alloc(8192L * 1808);   // shared region: fo (max 8192x1024) then fuse
    float* h1 = alloc(8192L * 512);
    float* h2 = alloc(8192L * 512);
    float* pred = alloc(8192L * 30);
    float* bnstat = alloc(512);
    int* nb   = (int*)alloc(8192L * KNB);
    int* nb1  = (int*)alloc(2048L * KNB);
    int* nb2  = (int*)alloc(512L * KNB);
    int* nbp1 = (int*)alloc(2048L * 4);
    int* nbp2 = (int*)alloc(512L * 4);
    int* n1   = (int*)alloc(8192);
    int* n2   = (int*)alloc(8192);

    auto nblk = [](long n, int b) { return (unsigned)((n + b - 1) / b); };

    // normalized directions + transposed head weights
    norm_dirs_kernel<<<nblk(896, 256), 256, 0, stream>>>(dir0, sd0, 896);
    norm_dirs_kernel<<<nblk(896, 256), 256, 0, stream>>>(dir1, sd1, 896);
    norm_dirs_kernel<<<nblk(1792, 256), 256, 0, stream>>>(dir2, sd2, 1792);
    norm_dirs_kernel<<<nblk(1792, 256), 256, 0, stream>>>(dir3, sd3, 1792);
    norm_dirs_kernel<<<nblk(3584, 256), 256, 0, stream>>>(dir4, sd4, 3584);
    transpose_kernel<<<nblk(512L * 1808, 256), 256, 0, stream>>>(wc1, wc1t, 512, 1808);
    transpose_kernel<<<nblk(512L * 512, 256), 256, 0, stream>>>(wc2, wc2t, 512, 512);
    transpose_kernel<<<nblk(30L * 512, 256), 256, 0, stream>>>(wc3, wc3t, 30, 512);

    // knn graphs (all point sets are prefixes of verts)
    knn_kernel<10><<<nblk(BSZ * 2048, 256), 256, 0, stream>>>(verts, 2048, 2048, nb);
    knn_kernel<10><<<nblk(BSZ * 512, 256), 256, 0, stream>>>(verts, 512, 512, nb1);
    knn_kernel<10><<<nblk(BSZ * 128, 256), 256, 0, stream>>>(verts, 128, 128, nb2);
    knn_kernel<4><<<nblk(BSZ * 512, 256), 256, 0, stream>>>(verts, 2048, 512, nbp1);
    knn_kernel<4><<<nblk(BSZ * 128, 256), 256, 0, stream>>>(verts, 512, 128, nbp2);

    // fm0 = conv_surface
    conv_surface_kernel<<<BSZ * 2048, 128, 0, stream>>>(verts, nb, sd0, fm0);

    // layer1: fo1 = fm0 @ w1 + b1 ; c1 = center+act ; bn ; relu
    gemm_kernel<<<dim3(16, 128), 256, 0, stream>>>(fm0, w1, b1, fbuf, 8192, 128, 1024, 0);
    conv_act_kernel<<<BSZ * 2048, 128, 0, stream>>>(verts, nb, sd1, fbuf, c1, 2048, 128);
    hipMemsetAsync(bnstat, 0, 2 * 128 * sizeof(float), stream);
    bn_stat_kernel<<<32, 128, 0, stream>>>(c1, bnstat, 8192, 128);
    bn_apply_relu_kernel<<<nblk(8192L * 128, 256), 256, 0, stream>>>(c1, bnstat, g_bn1, be_bn1, fm1, 8192, 128);

    // pool1 -> fp1 (first 512 verts)
    pool_kernel<<<nblk(BSZ * 512L * 128, 256), 256, 0, stream>>>(fm1, nbp1, fp1, 2048, 512, 128);

    // layer2
    gemm_kernel<<<dim3(32, 32), 256, 0, stream>>>(fp1, w2, b2, fbuf, 2048, 128, 2048, 0);
    conv_act_kernel<<<BSZ * 512, 256, 0, stream>>>(verts, nb1, sd2, fbuf, c2, 512, 256);
    hipMemsetAsync(bnstat, 0, 2 * 256 * sizeof(float), stream);
    bn_stat_kernel<<<32, 256, 0, stream>>>(c2, bnstat, 2048, 256);
    bn_apply_relu_kernel<<<nblk(2048L * 256, 256), 256, 0, stream>>>(c2, bnstat, g_bn2, be_bn2, fm2, 2048, 256);

    // layer3
    gemm_kernel<<<dim3(32, 32), 256, 0, stream>>>(fm2, w3, b3, fbuf, 2048, 256, 2048, 0);
    conv_act_kernel<<<BSZ * 512, 256, 0, stream>>>(verts, nb1, sd3, fbuf, c3, 512, 256);
    hipMemsetAsync(bnstat, 0, 2 * 256 * sizeof(float), stream);
    bn_stat_kernel<<<32, 256, 0, stream>>>(c3, bnstat, 2048, 256);
    bn_apply_relu_kernel<<<nblk(2048L * 256, 256), 256, 0, stream>>>(c3, bnstat, g_bn3, be_bn3, fm3, 2048, 256);

    // pool2 -> fp2 (first 128 verts)
    pool_kernel<<<nblk(BSZ * 128L * 256, 256), 256, 0, stream>>>(fm3, nbp2, fp2, 512, 128, 256);

    // layer4 (no bn, no relu)
    gemm_kernel<<<dim3(64, 8), 256, 0, stream>>>(fp2, w4, b4, fbuf, 512, 256, 4096, 0);
    conv_act_kernel<<<BSZ * 128, 512, 0, stream>>>(verts, nb2, sd4, fbuf, fm4, 128, 512);

    // global max + upsample indices
    fglob_kernel<<<nblk(BSZ * 512, 256), 256, 0, stream>>>(fm4, fg);
    nearest_kernel<<<nblk(BSZ * VN, 256), 256, 0, stream>>>(verts, 512, n1);
    nearest_kernel<<<nblk(BSZ * VN, 256), 256, 0, stream>>>(verts, 128, n2);

    // fuse (overwrites fo region - fo dead now), feat -> d_out
    fuse_kernel<<<nblk(8192L * 1808, 256), 256, 0, stream>>>(fm0, fm1, fm2, fm3, fm4, fg, onehot, n1, n2, fbuf);
    feat_kernel<<<nblk(8192L * 1296, 256), 256, 0, stream>>>(fbuf, outf + 245760);

    // MLP head
    gemm_kernel<<<dim3(8, 128), 256, 0, stream>>>(fbuf, wc1t, bc1, h1, 8192, 1808, 512, 1);
    gemm_kernel<<<dim3(8, 128), 256, 0, stream>>>(h1, wc2t, bc2, h2, 8192, 512, 512, 1);
    gemm_kernel<<<dim3(1, 128), 256, 0, stream>>>(h2, wc3t, bc3, pred, 8192, 512, 30, 0);
    pred_scatter_kernel<<<nblk(8192L * 30, 256), 256, 0, stream>>>(pred, outf);
}

// Round 2
// 1351.692 us; speedup vs baseline: 2.0149x; 2.0149x over previous
//
#include <hip/hip_runtime.h>
#include <math.h>

#define BSZ 4
#define VN 2048
#define SS 7
#define KNB 10

// ---------------------------------------------------------------- utilities

__global__ void norm_dirs_kernel(const float* __restrict__ d, float* __restrict__ sd, int C) {
    int c = blockIdx.x * blockDim.x + threadIdx.x;
    if (c >= C) return;
    float a = d[c], b = d[C + c], e = d[2 * C + c];
    float nrm = sqrtf(a * a + b * b + e * e);
    float den = fmaxf(nrm, 1e-12f);
    sd[c] = a / den; sd[C + c] = b / den; sd[2 * C + c] = e / den;
}

// (O, Cin) row-major -> (Cin, O) row-major
__global__ void transpose_kernel(const float* __restrict__ w, float* __restrict__ wt, int O, int Cin) {
    long i = blockIdx.x * 256L + threadIdx.x;
    if (i >= (long)O * Cin) return;
    int o = (int)(i / Cin), c = (int)(i % Cin);
    wt[(long)c * O + o] = w[i];
}

// ---------------------------------------------------------------- knn (split-source + merge)
// Partial top-K: block handles a tile of targets for one (batch, source-chunk).
// Sources staged in LDS. pd/pi layout: [b][i][chunk][KK].
template <int KK>
__global__ void knn_part_kernel(const float* __restrict__ verts, int Nsrc, int T, int nchunk,
                                float* __restrict__ pd, int* __restrict__ pi) {
    int bc = blockIdx.y;
    int b = bc / nchunk, c = bc % nchunk;
    int len = Nsrc / nchunk;
    extern __shared__ float smem[];
    float* sx = smem;
    float* sy = smem + len;
    float* sz = smem + 2 * len;
    const float* vb = verts + (long)b * VN * 3;
    int j0 = c * len;
    for (int j = threadIdx.x; j < len; j += blockDim.x) {
        sx[j] = vb[(j0 + j) * 3 + 0];
        sy[j] = vb[(j0 + j) * 3 + 1];
        sz[j] = vb[(j0 + j) * 3 + 2];
    }
    __syncthreads();
    int i = blockIdx.x * blockDim.x + threadIdx.x;
    if (i >= T) return;
    float px = vb[i * 3], py = vb[i * 3 + 1], pz = vb[i * 3 + 2];
    float d[KK]; int id[KK];
#pragma unroll
    for (int q = 0; q < KK; q++) { d[q] = 1e30f; id[q] = 0; }
    for (int j = 0; j < len; j++) {
        int jg = j0 + j;
        float dx = sx[j] - px, dy = sy[j] - py, dz = sz[j] - pz;
        float dd = dx * dx + dy * dy + dz * dz;
        if (jg != i && dd < d[KK - 1]) {
            int jj = jg;
#pragma unroll
            for (int q = 0; q < KK; q++) {
                if (dd < d[q]) {
                    float td = d[q]; d[q] = dd; dd = td;
                    int ti = id[q]; id[q] = jj; jj = ti;
                }
            }
        }
    }
    long base = (((long)b * T + i) * nchunk + c) * KK;
#pragma unroll
    for (int q = 0; q < KK; q++) { pd[base + q] = d[q]; pi[base + q] = id[q]; }
}

// Merge nchunk sorted partial lists into final top-K indices.
template <int KK>
__global__ void knn_merge_kernel(const float* __restrict__ pd, const int* __restrict__ pi,
                                 int T, int nchunk, int* __restrict__ out) {
    int t = blockIdx.x * blockDim.x + threadIdx.x;  // b*T + i
    if (t >= BSZ * T) return;
    float d[KK]; int id[KK];
#pragma unroll
    for (int q = 0; q < KK; q++) { d[q] = 1e30f; id[q] = 0; }
    for (int c = 0; c < nchunk; c++) {
        long base = ((long)t * nchunk + c) * KK;
        for (int q = 0; q < KK; q++) {
            float dd = pd[base + q];
            if (dd >= d[KK - 1]) break;  // partial list sorted ascending
            int jj = pi[base + q];
#pragma unroll
            for (int p = 0; p < KK; p++) {
                if (dd < d[p]) {
                    float td = d[p]; d[p] = dd; dd = td;
                    int ti = id[p]; id[p] = jj; jj = ti;
                }
            }
        }
    }
#pragma unroll
    for (int q = 0; q < KK; q++) out[(long)t * KK + q] = id[q];
}

// ---------------------------------------------------------------- conv_surface
__global__ void conv_surface_kernel(const float* __restrict__ verts, const int* __restrict__ nb,
                                    const float* __restrict__ sd, float* __restrict__ fm0) {
    int bv = blockIdx.x;
    int b = bv / VN, v = bv % VN;
    __shared__ float snd[KNB][3];
    int tid = threadIdx.x;
    if (tid < KNB) {
        int nj = nb[(long)bv * KNB + tid];
        const float* vb = verts + (long)b * VN * 3;
        float dx = vb[nj * 3] - vb[v * 3];
        float dy = vb[nj * 3 + 1] - vb[v * 3 + 1];
        float dz = vb[nj * 3 + 2] - vb[v * 3 + 2];
        float den = fmaxf(sqrtf(dx * dx + dy * dy + dz * dz), 1e-12f);
        snd[tid][0] = dx / den; snd[tid][1] = dy / den; snd[tid][2] = dz / den;
    }
    __syncthreads();
    int c = tid;
    float acc = 0.f;
    for (int s = 0; s < SS; s++) {
        int col = s * 128 + c;
        float s0 = sd[col], s1 = sd[896 + col], s2 = sd[2 * 896 + col];
        float m = 0.f;
#pragma unroll
        for (int n = 0; n < KNB; n++) {
            float dot = snd[n][0] * s0 + snd[n][1] * s1 + snd[n][2] * s2;
            m = fmaxf(m, dot);
        }
        acc += m;
    }
    fm0[(long)bv * 128 + c] = acc;
}

// ---------------------------------------------------------------- conv_layer act
__global__ void conv_act_kernel(const float* __restrict__ verts, const int* __restrict__ nb,
                                const float* __restrict__ sd, const float* __restrict__ fo,
                                float* __restrict__ out, int Vl, int outC) {
    int bv = blockIdx.x;
    int b = bv / Vl, v = bv % Vl;
    __shared__ float snd[KNB][3];
    __shared__ int srow[KNB];
    int tid = threadIdx.x;
    if (tid < KNB) {
        int nj = nb[(long)bv * KNB + tid];
        srow[tid] = b * Vl + nj;
        const float* vb = verts + (long)b * VN * 3;
        float dx = vb[nj * 3] - vb[v * 3];
        float dy = vb[nj * 3 + 1] - vb[v * 3 + 1];
        float dz = vb[nj * 3 + 2] - vb[v * 3 + 2];
        float den = fmaxf(sqrtf(dx * dx + dy * dy + dz * dz), 1e-12f);
        snd[tid][0] = dx / den; snd[tid][1] = dy / den; snd[tid][2] = dz / den;
    }
    __syncthreads();
    int c = tid;
    int SC = SS * outC;
    int foN = SC + outC;
    float acc = fo[(long)bv * foN + c];  // center
    for (int s = 0; s < SS; s++) {
        int col = s * outC + c;
        float s0 = sd[col], s1 = sd[SC + col], s2 = sd[2 * SC + col];
        float m = -1e30f;
#pragma unroll
        for (int n = 0; n < KNB; n++) {
            float dot = snd[n][0] * s0 + snd[n][1] * s1 + snd[n][2] * s2;
            float th = fmaxf(dot, 0.f);
            float sup = fo[(long)srow[n] * foN + outC + col];
            m = fmaxf(m, th * sup);
        }
        acc += m;
    }
    out[(long)bv * outC + c] = acc;
}

// ---------------------------------------------------------------- batchnorm
__global__ void bn_stat_kernel(const float* __restrict__ x, float* __restrict__ stat, int R, int C) {
    int c = threadIdx.x;
    int chunk = (R + gridDim.x - 1) / gridDim.x;
    int r0 = blockIdx.x * chunk;
    int r1 = min(r0 + chunk, R);
    float s = 0.f, s2 = 0.f;
    for (int r = r0; r < r1; r++) {
        float v = x[(long)r * C + c];
        s += v; s2 += v * v;
    }
    atomicAdd(&stat[c], s);
    atomicAdd(&stat[C + c], s2);
}

__global__ void bn_apply_relu_kernel(const float* __restrict__ x, const float* __restrict__ stat,
                                     const float* __restrict__ g, const float* __restrict__ be,
                                     float* __restrict__ out, int R, int C) {
    long i = blockIdx.x * 256L + threadIdx.x;
    if (i >= (long)R * C) return;
    int c = (int)(i % C);
    float mu = stat[c] / R;
    float var = stat[C + c] / R - mu * mu;
    var = fmaxf(var, 0.f);
    float y = (x[i] - mu) * rsqrtf(var + 1e-5f) * g[c] + be[c];
    out[i] = fmaxf(y, 0.f);
}

// ---------------------------------------------------------------- pool (max over 4 nbrs)
__global__ void pool_kernel(const float* __restrict__ fm, const int* __restrict__ idx,
                            float* __restrict__ out, int Vin, int T, int C) {
    long i = blockIdx.x * 256L + threadIdx.x;
    if (i >= (long)BSZ * T * C) return;
    int c = (int)(i % C);
    long bt = i / C;
    int b = (int)(bt / T), t = (int)(bt % T);
    const int* id = idx + ((long)b * T + t) * 4;
    float m = -1e30f;
#pragma unroll
    for (int n = 0; n < 4; n++)
        m = fmaxf(m, fm[((long)b * Vin + id[n]) * C + c]);
    out[i] = m;
}

// ---------------------------------------------------------------- GEMM  C = A(M,K) @ B(K,N) + bias, opt relu
__global__ __launch_bounds__(256) void gemm_kernel(const float* __restrict__ A, const float* __restrict__ B,
                                                   const float* __restrict__ bias, float* __restrict__ C,
                                                   int M, int K, int N, int do_relu) {
    __shared__ float As[16][68];
    __shared__ float Bs[16][68];
    int tid = threadIdx.x;
    int tx = tid % 16, ty = tid / 16;
    int m0 = blockIdx.y * 64, n0 = blockIdx.x * 64;
    float acc[4][4] = {};
    int aRow = tid / 4;
    int aK = (tid % 4) * 4;
    int bK = tid / 16;
    int bN = (tid % 16) * 4;
    bool nfull = (n0 + 64 <= N) && ((N & 3) == 0);
    for (int k0 = 0; k0 < K; k0 += 16) {
        float4 av = *(const float4*)(A + (long)(m0 + aRow) * K + k0 + aK);
        As[aK + 0][aRow] = av.x; As[aK + 1][aRow] = av.y;
        As[aK + 2][aRow] = av.z; As[aK + 3][aRow] = av.w;
        if (nfull) {
            float4 bv = *(const float4*)(B + (long)(k0 + bK) * N + n0 + bN);
            Bs[bK][bN] = bv.x; Bs[bK][bN + 1] = bv.y; Bs[bK][bN + 2] = bv.z; Bs[bK][bN + 3] = bv.w;
        } else {
#pragma unroll
            for (int j = 0; j < 4; j++) {
                int n = n0 + bN + j;
                Bs[bK][bN + j] = (n < N) ? B[(long)(k0 + bK) * N + n] : 0.f;
            }
        }
        __syncthreads();
#pragma unroll
        for (int kk = 0; kk < 16; kk++) {
            float4 a4 = *(const float4*)&As[kk][ty * 4];
            float4 b4 = *(const float4*)&Bs[kk][tx * 4];
            float a[4] = {a4.x, a4.y, a4.z, a4.w};
            float bb[4] = {b4.x, b4.y, b4.z, b4.w};
#pragma unroll
            for (int ii = 0; ii < 4; ii++)
#pragma unroll
                for (int jj = 0; jj < 4; jj++)
                    acc[ii][jj] += a[ii] * bb[jj];
        }
        __syncthreads();
    }
#pragma unroll
    for (int ii = 0; ii < 4; ii++) {
        int m = m0 + ty * 4 + ii;
#pragma unroll
        for (int jj = 0; jj < 4; jj++) {
            int n = n0 + tx * 4 + jj;
            if (n < N) {
                float v = acc[ii][jj] + bias[n];
                if (do_relu) v = fmaxf(v, 0.f);
                C[(long)m * N + n] = v;
            }
        }
    }
}

// ---------------------------------------------------------------- global max over 128 rows
__global__ void fglob_kernel(const float* __restrict__ fm4, float* __restrict__ fg) {
    int t = blockIdx.x * blockDim.x + threadIdx.x;
    if (t >= BSZ * 512) return;
    int b = t / 512, c = t % 512;
    float m = -1e30f;
    for (int r = 0; r < 128; r++)
        m = fmaxf(m, fm4[((long)b * 128 + r) * 512 + c]);
    fg[t] = m;
}

// ---------------------------------------------------------------- nearest source index (LDS-staged)
__global__ void nearest_kernel(const float* __restrict__ verts, int SN, int* __restrict__ out) {
    extern __shared__ float smem[];
    float* sx = smem;
    float* sy = smem + SN;
    float* sz = smem + 2 * SN;
    int t = blockIdx.x * blockDim.x + threadIdx.x;
    int b = t / VN;  // VN % blockDim == 0 -> block-uniform b
    const float* vb = verts + (long)b * VN * 3;
    for (int j = threadIdx.x; j < SN; j += blockDim.x) {
        sx[j] = vb[j * 3]; sy[j] = vb[j * 3 + 1]; sz[j] = vb[j * 3 + 2];
    }
    __syncthreads();
    int i = t % VN;
    float px = vb[i * 3], py = vb[i * 3 + 1], pz = vb[i * 3 + 2];
    float best = 1e30f; int bi = 0;
    for (int j = 0; j < SN; j++) {
        float dx = sx[j] - px, dy = sy[j] - py, dz = sz[j] - pz;
        float dd = dx * dx + dy * dy + dz * dz;
        bool lt = dd < best;
        best = lt ? dd : best;
        bi = lt ? j : bi;
    }
    out[t] = bi;
}

// ---------------------------------------------------------------- fuse assembly
__global__ void fuse_kernel(const float* __restrict__ fm0, const float* __restrict__ fm1,
                            const float* __restrict__ fm2, const float* __restrict__ fm3,
                            const float* __restrict__ fm4, const float* __restrict__ fg,
                            const float* __restrict__ onehot,
                            const int* __restrict__ n1, const int* __restrict__ n2,
                            float* __restrict__ fuse) {
    long i = blockIdx.x * 256L + threadIdx.x;
    if (i >= 8192L * 1808) return;
    int c = (int)(i % 1808);
    long row = i / 1808;
    int b = (int)(row / VN);
    float val;
    if (c < 128)       val = fm0[row * 128 + c];
    else if (c < 256)  val = fm1[row * 128 + (c - 128)];
    else if (c < 512)  val = fm2[((long)b * 512 + n1[row]) * 256 + (c - 256)];
    else if (c < 768)  val = fm3[((long)b * 512 + n1[row]) * 256 + (c - 512)];
    else if (c < 1280) val = fm4[((long)b * 128 + n2[row]) * 512 + (c - 768)];
    else if (c < 1792) val = fg[b * 512 + (c - 1280)];
    else               val = onehot[b * 16 + (c - 1792)];
    fuse[i] = val;
}

__global__ void feat_kernel(const float* __restrict__ fuse, float* __restrict__ feat) {
    long i = blockIdx.x * 256L + threadIdx.x;
    if (i >= 8192L * 1296) return;
    int cf = (int)(i % 1296);
    long row = i / 1296;
    int c = (cf < 1280) ? cf : cf + 512;  // skip fg block
    feat[i] = fuse[row * 1808 + c];
}

__global__ void pred_scatter_kernel(const float* __restrict__ pred, float* __restrict__ out) {
    long i = blockIdx.x * 256L + threadIdx.x;
    if (i >= 8192L * 30) return;
    int c = (int)(i % 30);
    long row = i / 30;
    float v = pred[i];
    if (c < 6) out[row * 6 + c] = v;
    else       out[49152 + row * 24 + (c - 6)] = v;
}

// ---------------------------------------------------------------- launch

extern "C" void kernel_launch(void* const* d_in, const int* in_sizes, int n_in,
                              void* d_out, int out_size, void* d_ws, size_t ws_size,
                              hipStream_t stream) {
    const float* verts  = (const float*)d_in[0];
    const float* onehot = (const float*)d_in[1];
    const float* dir0 = (const float*)d_in[2];
    const float* w1 = (const float*)d_in[3];
    const float* b1 = (const float*)d_in[4];
    const float* dir1 = (const float*)d_in[5];
    const float* w2 = (const float*)d_in[6];
    const float* b2 = (const float*)d_in[7];
    const float* dir2 = (const float*)d_in[8];
    const float* w3 = (const float*)d_in[9];
    const float* b3 = (const float*)d_in[10];
    const float* dir3 = (const float*)d_in[11];
    const float* w4 = (const float*)d_in[12];
    const float* b4 = (const float*)d_in[13];
    const float* dir4 = (const float*)d_in[14];
    const float* g_bn1 = (const float*)d_in[15];
    const float* be_bn1 = (const float*)d_in[16];
    const float* g_bn2 = (const float*)d_in[17];
    const float* be_bn2 = (const float*)d_in[18];
    const float* g_bn3 = (const float*)d_in[19];
    const float* be_bn3 = (const float*)d_in[20];
    const float* wc1 = (const float*)d_in[21];
    const float* bc1 = (const float*)d_in[22];
    const float* wc2 = (const float*)d_in[23];
    const float* bc2 = (const float*)d_in[24];
    const float* wc3 = (const float*)d_in[25];
    const float* bc3 = (const float*)d_in[26];
    float* outf = (float*)d_out;

    float* wsf = (float*)d_ws;
    size_t off = 0;
    auto alloc = [&](size_t n) { float* p = wsf + off; off += (n + 15) & ~(size_t)15; return p; };

    float* sd0 = alloc(3 * 896);
    float* sd1 = alloc(3 * 896);
    float* sd2 = alloc(3 * 1792);
    float* sd3 = alloc(3 * 1792);
    float* sd4 = alloc(3 * 3584);
    float* wc1t = alloc(1808L * 512);
    float* wc2t = alloc(512L * 512);
    float* wc3t = alloc(512L * 30);
    float* fm0 = alloc(8192L * 128);
    float* fm1 = alloc(8192L * 128);
    float* c1  = alloc(8192L * 128);
    float* fp1 = alloc(2048L * 128);
    float* fm2 = alloc(2048L * 256);
    float* c2  = alloc(2048L * 256);
    float* fm3 = alloc(2048L * 256);
    float* c3  = alloc(2048L * 256);
    float* fp2 = alloc(512L * 256);
    float* fm4 = alloc(512L * 512);
    float* fg  = alloc(BSZ * 512);
    float* fbuf = alloc(8192L * 1808);   // shared: fo (max 8192x1024) then fuse
    float* h1 = alloc(8192L * 512);
    float* h2 = alloc(8192L * 512);
    float* pred = alloc(8192L * 30);
    float* bnstat = alloc(512);
    float* pd  = alloc(8192L * 8 * KNB);           // knn partial dists (reused)
    int* pi    = (int*)alloc(8192L * 8 * KNB);     // knn partial idx
    int* nb   = (int*)alloc(8192L * KNB);
    int* nb1  = (int*)alloc(2048L * KNB);
    int* nb2  = (int*)alloc(512L * KNB);
    int* nbp1 = (int*)alloc(2048L * 4);
    int* nbp2 = (int*)alloc(512L * 4);
    int* n1   = (int*)alloc(8192);
    int* n2   = (int*)alloc(8192);

    auto nblk = [](long n, int b) { return (unsigned)((n + b - 1) / b); };

    norm_dirs_kernel<<<nblk(896, 256), 256, 0, stream>>>(dir0, sd0, 896);
    norm_dirs_kernel<<<nblk(896, 256), 256, 0, stream>>>(dir1, sd1, 896);
    norm_dirs_kernel<<<nblk(1792, 256), 256, 0, stream>>>(dir2, sd2, 1792);
    norm_dirs_kernel<<<nblk(1792, 256), 256, 0, stream>>>(dir3, sd3, 1792);
    norm_dirs_kernel<<<nblk(3584, 256), 256, 0, stream>>>(dir4, sd4, 3584);
    transpose_kernel<<<nblk(512L * 1808, 256), 256, 0, stream>>>(wc1, wc1t, 512, 1808);
    transpose_kernel<<<nblk(512L * 512, 256), 256, 0, stream>>>(wc2, wc2t, 512, 512);
    transpose_kernel<<<nblk(30L * 512, 256), 256, 0, stream>>>(wc3, wc3t, 30, 512);

    // ---- knn graphs: split-source partial top-K + merge ----
    // nb: T=2048, Nsrc=2048, K=10, nchunk=8 (len 256)
    knn_part_kernel<10><<<dim3(8, BSZ * 8), 256, 3 * 256 * 4, stream>>>(verts, 2048, 2048, 8, pd, pi);
    knn_merge_kernel<10><<<nblk(BSZ * 2048, 256), 256, 0, stream>>>(pd, pi, 2048, 8, nb);
    // nb1: T=512, Nsrc=512, K=10, nchunk=4 (len 128)
    knn_part_kernel<10><<<dim3(2, BSZ * 4), 256, 3 * 128 * 4, stream>>>(verts, 512, 512, 4, pd, pi);
    knn_merge_kernel<10><<<nblk(BSZ * 512, 256), 256, 0, stream>>>(pd, pi, 512, 4, nb1);
    // nb2: T=128, Nsrc=128, K=10, nchunk=1 (len 128)
    knn_part_kernel<10><<<dim3(1, BSZ * 1), 128, 3 * 128 * 4, stream>>>(verts, 128, 128, 1, pd, pi);
    knn_merge_kernel<10><<<nblk(BSZ * 128, 128), 128, 0, stream>>>(pd, pi, 128, 1, nb2);
    // nbp1: T=512, Nsrc=2048, K=4, nchunk=8 (len 256)
    knn_part_kernel<4><<<dim3(2, BSZ * 8), 256, 3 * 256 * 4, stream>>>(verts, 2048, 512, 8, pd, pi);
    knn_merge_kernel<4><<<nblk(BSZ * 512, 256), 256, 0, stream>>>(pd, pi, 512, 8, nbp1);
    // nbp2: T=128, Nsrc=512, K=4, nchunk=4 (len 128)
    knn_part_kernel<4><<<dim3(1, BSZ * 4), 128, 3 * 128 * 4, stream>>>(verts, 512, 128, 4, pd, pi);
    knn_merge_kernel<4><<<nblk(BSZ * 128, 128), 128, 0, stream>>>(pd, pi, 128, 4, nbp2);

    // fm0 = conv_surface
    conv_surface_kernel<<<BSZ * 2048, 128, 0, stream>>>(verts, nb, sd0, fm0);

    // layer1
    gemm_kernel<<<dim3(16, 128), 256, 0, stream>>>(fm0, w1, b1, fbuf, 8192, 128, 1024, 0);
    conv_act_kernel<<<BSZ * 2048, 128, 0, stream>>>(verts, nb, sd1, fbuf, c1, 2048, 128);
    hipMemsetAsync(bnstat, 0, 2 * 128 * sizeof(float), stream);
    bn_stat_kernel<<<32, 128, 0, stream>>>(c1, bnstat, 8192, 128);
    bn_apply_relu_kernel<<<nblk(8192L * 128, 256), 256, 0, stream>>>(c1, bnstat, g_bn1, be_bn1, fm1, 8192, 128);

    // pool1
    pool_kernel<<<nblk(BSZ * 512L * 128, 256), 256, 0, stream>>>(fm1, nbp1, fp1, 2048, 512, 128);

    // layer2
    gemm_kernel<<<dim3(32, 32), 256, 0, stream>>>(fp1, w2, b2, fbuf, 2048, 128, 2048, 0);
    conv_act_kernel<<<BSZ * 512, 256, 0, stream>>>(verts, nb1, sd2, fbuf, c2, 512, 256);
    hipMemsetAsync(bnstat, 0, 2 * 256 * sizeof(float), stream);
    bn_stat_kernel<<<32, 256, 0, stream>>>(c2, bnstat, 2048, 256);
    bn_apply_relu_kernel<<<nblk(2048L * 256, 256), 256, 0, stream>>>(c2, bnstat, g_bn2, be_bn2, fm2, 2048, 256);

    // layer3
    gemm_kernel<<<dim3(32, 32), 256, 0, stream>>>(fm2, w3, b3, fbuf, 2048, 256, 2048, 0);
    conv_act_kernel<<<BSZ * 512, 256, 0, stream>>>(verts, nb1, sd3, fbuf, c3, 512, 256);
    hipMemsetAsync(bnstat, 0, 2 * 256 * sizeof(float), stream);
    bn_stat_kernel<<<32, 256, 0, stream>>>(c3, bnstat, 2048, 256);
    bn_apply_relu_kernel<<<nblk(2048L * 256, 256), 256, 0, stream>>>(c3, bnstat, g_bn3, be_bn3, fm3, 2048, 256);

    // pool2
    pool_kernel<<<nblk(BSZ * 128L * 256, 256), 256, 0, stream>>>(fm3, nbp2, fp2, 512, 128, 256);

    // layer4
    gemm_kernel<<<dim3(64, 8), 256, 0, stream>>>(fp2, w4, b4, fbuf, 512, 256, 4096, 0);
    conv_act_kernel<<<BSZ * 128, 512, 0, stream>>>(verts, nb2, sd4, fbuf, fm4, 128, 512);

    // global max + upsample indices
    fglob_kernel<<<nblk(BSZ * 512, 256), 256, 0, stream>>>(fm4, fg);
    nearest_kernel<<<nblk(BSZ * VN, 256), 256, 3 * 512 * 4, stream>>>(verts, 512, n1);
    nearest_kernel<<<nblk(BSZ * VN, 256), 256, 3 * 128 * 4, stream>>>(verts, 128, n2);

    // fuse + feat
    fuse_kernel<<<nblk(8192L * 1808, 256), 256, 0, stream>>>(fm0, fm1, fm2, fm3, fm4, fg, onehot, n1, n2, fbuf);
    feat_kernel<<<nblk(8192L * 1296, 256), 256, 0, stream>>>(fbuf, outf + 245760);

    // MLP head
    gemm_kernel<<<dim3(8, 128), 256, 0, stream>>>(fbuf, wc1t, bc1, h1, 8192, 1808, 512, 1);
    gemm_kernel<<<dim3(8, 128), 256, 0, stream>>>(h1, wc2t, bc2, h2, 8192, 512, 512, 1);
    gemm_kernel<<<dim3(1, 128), 256, 0, stream>>>(h2, wc3t, bc3, pred, 8192, 512, 30, 0);
    pred_scatter_kernel<<<nblk(8192L * 30, 256), 256, 0, stream>>>(pred, outf);
}

// Round 3
// 1109.769 us; speedup vs baseline: 2.4542x; 1.2180x over previous
//
#include <hip/hip_runtime.h>
#include <hip/hip_bf16.h>
#include <math.h>

#define BSZ 4
#define VN 2048
#define SS 7
#define KNB 10

typedef __attribute__((ext_vector_type(8))) short short8;
typedef __attribute__((ext_vector_type(4))) float f32x4;

__device__ inline ushort f2bf(float x) {
    __hip_bfloat16 h = __float2bfloat16(x);
    return *(ushort*)&h;
}

// ---------------------------------------------------------------- utilities

__global__ void norm_dirs_kernel(const float* __restrict__ d, float* __restrict__ sd, int C) {
    int c = blockIdx.x * blockDim.x + threadIdx.x;
    if (c >= C) return;
    float a = d[c], b = d[C + c], e = d[2 * C + c];
    float nrm = sqrtf(a * a + b * b + e * e);
    float den = fmaxf(nrm, 1e-12f);
    sd[c] = a / den; sd[C + c] = b / den; sd[2 * C + c] = e / den;
}

// (O, Cin) row-major -> (Cin, O) row-major
__global__ void transpose_kernel(const float* __restrict__ w, float* __restrict__ wt, int O, int Cin) {
    long i = blockIdx.x * 256L + threadIdx.x;
    if (i >= (long)O * Cin) return;
    int o = (int)(i / Cin), c = (int)(i % Cin);
    wt[(long)c * O + o] = w[i];
}

// fp32 (rows,cin) -> bf16 (rows,cpad), zero pad
__global__ void f2b_pad_kernel(const float* __restrict__ src, ushort* __restrict__ dst,
                               long rows, int cin, int cpad) {
    long i = blockIdx.x * 256L + threadIdx.x;
    if (i >= rows * cpad) return;
    int c = (int)(i % cpad);
    long r = i / cpad;
    float v = (c < cin) ? src[r * cin + c] : 0.f;
    dst[i] = f2bf(v);
}

// ---------------------------------------------------------------- knn (split-source + merge)
template <int KK>
__global__ void knn_part_kernel(const float* __restrict__ verts, int Nsrc, int T, int nchunk,
                                float* __restrict__ pd, int* __restrict__ pi) {
    int bc = blockIdx.y;
    int b = bc / nchunk, c = bc % nchunk;
    int len = Nsrc / nchunk;
    extern __shared__ float smem[];
    float* sx = smem;
    float* sy = smem + len;
    float* sz = smem + 2 * len;
    const float* vb = verts + (long)b * VN * 3;
    int j0 = c * len;
    for (int j = threadIdx.x; j < len; j += blockDim.x) {
        sx[j] = vb[(j0 + j) * 3 + 0];
        sy[j] = vb[(j0 + j) * 3 + 1];
        sz[j] = vb[(j0 + j) * 3 + 2];
    }
    __syncthreads();
    int i = blockIdx.x * blockDim.x + threadIdx.x;
    if (i >= T) return;
    float px = vb[i * 3], py = vb[i * 3 + 1], pz = vb[i * 3 + 2];
    float d[KK]; int id[KK];
#pragma unroll
    for (int q = 0; q < KK; q++) { d[q] = 1e30f; id[q] = 0; }
    for (int j = 0; j < len; j++) {
        int jg = j0 + j;
        float dx = sx[j] - px, dy = sy[j] - py, dz = sz[j] - pz;
        float dd = dx * dx + dy * dy + dz * dz;
        if (jg != i && dd < d[KK - 1]) {
            int jj = jg;
#pragma unroll
            for (int q = 0; q < KK; q++) {
                if (dd < d[q]) {
                    float td = d[q]; d[q] = dd; dd = td;
                    int ti = id[q]; id[q] = jj; jj = ti;
                }
            }
        }
    }
    long base = (((long)b * T + i) * nchunk + c) * KK;
#pragma unroll
    for (int q = 0; q < KK; q++) { pd[base + q] = d[q]; pi[base + q] = id[q]; }
}

template <int KK>
__global__ void knn_merge_kernel(const float* __restrict__ pd, const int* __restrict__ pi,
                                 int T, int nchunk, int* __restrict__ out) {
    int t = blockIdx.x * blockDim.x + threadIdx.x;
    if (t >= BSZ * T) return;
    float d[KK]; int id[KK];
#pragma unroll
    for (int q = 0; q < KK; q++) { d[q] = 1e30f; id[q] = 0; }
    for (int c = 0; c < nchunk; c++) {
        long base = ((long)t * nchunk + c) * KK;
        for (int q = 0; q < KK; q++) {
            float dd = pd[base + q];
            if (dd >= d[KK - 1]) break;
            int jj = pi[base + q];
#pragma unroll
            for (int p = 0; p < KK; p++) {
                if (dd < d[p]) {
                    float td = d[p]; d[p] = dd; dd = td;
                    int ti = id[p]; id[p] = jj; jj = ti;
                }
            }
        }
    }
#pragma unroll
    for (int q = 0; q < KK; q++) out[(long)t * KK + q] = id[q];
}

// ---------------------------------------------------------------- conv_surface
__global__ void conv_surface_kernel(const float* __restrict__ verts, const int* __restrict__ nb,
                                    const float* __restrict__ sd, float* __restrict__ fm0) {
    int bv = blockIdx.x;
    int b = bv / VN, v = bv % VN;
    __shared__ float snd[KNB][3];
    int tid = threadIdx.x;
    if (tid < KNB) {
        int nj = nb[(long)bv * KNB + tid];
        const float* vb = verts + (long)b * VN * 3;
        float dx = vb[nj * 3] - vb[v * 3];
        float dy = vb[nj * 3 + 1] - vb[v * 3 + 1];
        float dz = vb[nj * 3 + 2] - vb[v * 3 + 2];
        float den = fmaxf(sqrtf(dx * dx + dy * dy + dz * dz), 1e-12f);
        snd[tid][0] = dx / den; snd[tid][1] = dy / den; snd[tid][2] = dz / den;
    }
    __syncthreads();
    int c = tid;
    float acc = 0.f;
    for (int s = 0; s < SS; s++) {
        int col = s * 128 + c;
        float s0 = sd[col], s1 = sd[896 + col], s2 = sd[2 * 896 + col];
        float m = 0.f;
#pragma unroll
        for (int n = 0; n < KNB; n++) {
            float dot = snd[n][0] * s0 + snd[n][1] * s1 + snd[n][2] * s2;
            m = fmaxf(m, dot);
        }
        acc += m;
    }
    fm0[(long)bv * 128 + c] = acc;
}

// ---------------------------------------------------------------- conv_layer act
__global__ void conv_act_kernel(const float* __restrict__ verts, const int* __restrict__ nb,
                                const float* __restrict__ sd, const float* __restrict__ fo,
                                float* __restrict__ out, int Vl, int outC) {
    int bv = blockIdx.x;
    int b = bv / Vl, v = bv % Vl;
    __shared__ float snd[KNB][3];
    __shared__ int srow[KNB];
    int tid = threadIdx.x;
    if (tid < KNB) {
        int nj = nb[(long)bv * KNB + tid];
        srow[tid] = b * Vl + nj;
        const float* vb = verts + (long)b * VN * 3;
        float dx = vb[nj * 3] - vb[v * 3];
        float dy = vb[nj * 3 + 1] - vb[v * 3 + 1];
        float dz = vb[nj * 3 + 2] - vb[v * 3 + 2];
        float den = fmaxf(sqrtf(dx * dx + dy * dy + dz * dz), 1e-12f);
        snd[tid][0] = dx / den; snd[tid][1] = dy / den; snd[tid][2] = dz / den;
    }
    __syncthreads();
    int c = tid;
    int SC = SS * outC;
    int foN = SC + outC;
    float acc = fo[(long)bv * foN + c];  // center
    for (int s = 0; s < SS; s++) {
        int col = s * outC + c;
        float s0 = sd[col], s1 = sd[SC + col], s2 = sd[2 * SC + col];
        float m = -1e30f;
#pragma unroll
        for (int n = 0; n < KNB; n++) {
            float dot = snd[n][0] * s0 + snd[n][1] * s1 + snd[n][2] * s2;
            float th = fmaxf(dot, 0.f);
            float sup = fo[(long)srow[n] * foN + outC + col];
            m = fmaxf(m, th * sup);
        }
        acc += m;
    }
    out[(long)bv * outC + c] = acc;
}

// ---------------------------------------------------------------- batchnorm
__global__ void bn_stat_kernel(const float* __restrict__ x, float* __restrict__ stat, int R, int C) {
    int c = threadIdx.x;
    int chunk = (R + gridDim.x - 1) / gridDim.x;
    int r0 = blockIdx.x * chunk;
    int r1 = min(r0 + chunk, R);
    float s = 0.f, s2 = 0.f;
    for (int r = r0; r < r1; r++) {
        float v = x[(long)r * C + c];
        s += v; s2 += v * v;
    }
    atomicAdd(&stat[c], s);
    atomicAdd(&stat[C + c], s2);
}

__global__ void bn_apply_relu_kernel(const float* __restrict__ x, const float* __restrict__ stat,
                                     const float* __restrict__ g, const float* __restrict__ be,
                                     float* __restrict__ out, int R, int C) {
    long i = blockIdx.x * 256L + threadIdx.x;
    if (i >= (long)R * C) return;
    int c = (int)(i % C);
    float mu = stat[c] / R;
    float var = stat[C + c] / R - mu * mu;
    var = fmaxf(var, 0.f);
    float y = (x[i] - mu) * rsqrtf(var + 1e-5f) * g[c] + be[c];
    out[i] = fmaxf(y, 0.f);
}

// ---------------------------------------------------------------- pool (max over 4 nbrs)
__global__ void pool_kernel(const float* __restrict__ fm, const int* __restrict__ idx,
                            float* __restrict__ out, int Vin, int T, int C) {
    long i = blockIdx.x * 256L + threadIdx.x;
    if (i >= (long)BSZ * T * C) return;
    int c = (int)(i % C);
    long bt = i / C;
    int b = (int)(bt / T), t = (int)(bt % T);
    const int* id = idx + ((long)b * T + t) * 4;
    float m = -1e30f;
#pragma unroll
    for (int n = 0; n < 4; n++)
        m = fmaxf(m, fm[((long)b * Vin + id[n]) * C + c]);
    out[i] = m;
}

// ---------------------------------------------------------------- fp32 GEMM  C = A(M,K) @ B(K,N) + bias
__global__ __launch_bounds__(256) void gemm_kernel(const float* __restrict__ A, const float* __restrict__ B,
                                                   const float* __restrict__ bias, float* __restrict__ C,
                                                   int M, int K, int N, int do_relu) {
    __shared__ float As[16][68];
    __shared__ float Bs[16][68];
    int tid = threadIdx.x;
    int tx = tid % 16, ty = tid / 16;
    int m0 = blockIdx.y * 64, n0 = blockIdx.x * 64;
    float acc[4][4] = {};
    int aRow = tid / 4;
    int aK = (tid % 4) * 4;
    int bK = tid / 16;
    int bN = (tid % 16) * 4;
    bool nfull = (n0 + 64 <= N) && ((N & 3) == 0);
    for (int k0 = 0; k0 < K; k0 += 16) {
        float4 av = *(const float4*)(A + (long)(m0 + aRow) * K + k0 + aK);
        As[aK + 0][aRow] = av.x; As[aK + 1][aRow] = av.y;
        As[aK + 2][aRow] = av.z; As[aK + 3][aRow] = av.w;
        if (nfull) {
            float4 bv = *(const float4*)(B + (long)(k0 + bK) * N + n0 + bN);
            Bs[bK][bN] = bv.x; Bs[bK][bN + 1] = bv.y; Bs[bK][bN + 2] = bv.z; Bs[bK][bN + 3] = bv.w;
        } else {
#pragma unroll
            for (int j = 0; j < 4; j++) {
                int n = n0 + bN + j;
                Bs[bK][bN + j] = (n < N) ? B[(long)(k0 + bK) * N + n] : 0.f;
            }
        }
        __syncthreads();
#pragma unroll
        for (int kk = 0; kk < 16; kk++) {
            float4 a4 = *(const float4*)&As[kk][ty * 4];
            float4 b4 = *(const float4*)&Bs[kk][tx * 4];
            float a[4] = {a4.x, a4.y, a4.z, a4.w};
            float bb[4] = {b4.x, b4.y, b4.z, b4.w};
#pragma unroll
            for (int ii = 0; ii < 4; ii++)
#pragma unroll
                for (int jj = 0; jj < 4; jj++)
                    acc[ii][jj] += a[ii] * bb[jj];
        }
        __syncthreads();
    }
#pragma unroll
    for (int ii = 0; ii < 4; ii++) {
        int m = m0 + ty * 4 + ii;
#pragma unroll
        for (int jj = 0; jj < 4; jj++) {
            int n = n0 + tx * 4 + jj;
            if (n < N) {
                float v = acc[ii][jj] + bias[n];
                if (do_relu) v = fmaxf(v, 0.f);
                C[(long)m * N + n] = v;
            }
        }
    }
}

// ---------------------------------------------------------------- bf16 MFMA GEMM
// C(M,N) = A(M,K)bf16 @ Bt(N,K)bf16^T + bias, fp32 accumulate.
// Requires M%128==0, N%128==0, K%32==0. 128x128 tile, 4 waves (2x2), 4x4 MFMA frags each.
__global__ __launch_bounds__(256) void gemm_mfma_bt_kernel(
    const ushort* __restrict__ A, const ushort* __restrict__ Bt,
    const float* __restrict__ bias, float* __restrict__ Cf, ushort* __restrict__ Cb,
    int M, int N, int K, int relu)
{
    __shared__ ushort As[128 * 32];
    __shared__ ushort Bs[128 * 32];
    int t = threadIdx.x;
    int w = t >> 6, l = t & 63;
    int quad = l >> 4, lm = l & 15;
    int wm = w >> 1, wn = w & 1;
    long m0 = blockIdx.y * 128L;
    long n0 = blockIdx.x * 128L;
    int lr = t >> 2;          // 0..63 staging row
    int lk = (t & 3) * 8;     // staging k-offset (elements)
    f32x4 acc[4][4];
#pragma unroll
    for (int i = 0; i < 4; i++)
#pragma unroll
        for (int j = 0; j < 4; j++) acc[i][j] = (f32x4){0.f, 0.f, 0.f, 0.f};

    for (int k0 = 0; k0 < K; k0 += 32) {
        uint4 a0 = *(const uint4*)(A + (m0 + lr) * K + k0 + lk);
        uint4 a1 = *(const uint4*)(A + (m0 + 64 + lr) * K + k0 + lk);
        uint4 b0 = *(const uint4*)(Bt + (n0 + lr) * K + k0 + lk);
        uint4 b1 = *(const uint4*)(Bt + (n0 + 64 + lr) * K + k0 + lk);
        __syncthreads();  // prev-iter LDS reads done before overwrite
        *(uint4*)&As[lr * 32 + lk] = a0;
        *(uint4*)&As[(64 + lr) * 32 + lk] = a1;
        *(uint4*)&Bs[lr * 32 + lk] = b0;
        *(uint4*)&Bs[(64 + lr) * 32 + lk] = b1;
        __syncthreads();
        short8 af[4], bfr[4];
#pragma unroll
        for (int i = 0; i < 4; i++)
            af[i] = *(const short8*)&As[(wm * 64 + i * 16 + lm) * 32 + quad * 8];
#pragma unroll
        for (int j = 0; j < 4; j++)
            bfr[j] = *(const short8*)&Bs[(wn * 64 + j * 16 + lm) * 32 + quad * 8];
#pragma unroll
        for (int i = 0; i < 4; i++)
#pragma unroll
            for (int j = 0; j < 4; j++)
                acc[i][j] = __builtin_amdgcn_mfma_f32_16x16x32_bf16(af[i], bfr[j], acc[i][j], 0, 0, 0);
    }
    // epilogue: C/D layout col=lane&15, row=(lane>>4)*4+reg
#pragma unroll
    for (int i = 0; i < 4; i++) {
#pragma unroll
        for (int j = 0; j < 4; j++) {
            int n = (int)n0 + wn * 64 + j * 16 + lm;
            float bv = bias[n];
#pragma unroll
            for (int r = 0; r < 4; r++) {
                int m = (int)m0 + wm * 64 + i * 16 + quad * 4 + r;
                float v = acc[i][j][r] + bv;
                if (relu) v = fmaxf(v, 0.f);
                if (Cf) Cf[(long)m * N + n] = v;
                if (Cb) Cb[(long)m * N + n] = f2bf(v);
            }
        }
    }
}

// ---------------------------------------------------------------- global max over 128 rows
__global__ void fglob_kernel(const float* __restrict__ fm4, float* __restrict__ fg) {
    int t = blockIdx.x * blockDim.x + threadIdx.x;
    if (t >= BSZ * 512) return;
    int b = t / 512, c = t % 512;
    float m = -1e30f;
    for (int r = 0; r < 128; r++)
        m = fmaxf(m, fm4[((long)b * 128 + r) * 512 + c]);
    fg[t] = m;
}

// ---------------------------------------------------------------- nearest source index (LDS-staged)
__global__ void nearest_kernel(const float* __restrict__ verts, int SN, int* __restrict__ out) {
    extern __shared__ float smem[];
    float* sx = smem;
    float* sy = smem + SN;
    float* sz = smem + 2 * SN;
    int t = blockIdx.x * blockDim.x + threadIdx.x;
    int b = t / VN;
    const float* vb = verts + (long)b * VN * 3;
    for (int j = threadIdx.x; j < SN; j += blockDim.x) {
        sx[j] = vb[j * 3]; sy[j] = vb[j * 3 + 1]; sz[j] = vb[j * 3 + 2];
    }
    __syncthreads();
    int i = t % VN;
    float px = vb[i * 3], py = vb[i * 3 + 1], pz = vb[i * 3 + 2];
    float best = 1e30f; int bi = 0;
    for (int j = 0; j < SN; j++) {
        float dx = sx[j] - px, dy = sy[j] - py, dz = sz[j] - pz;
        float dd = dx * dx + dy * dy + dz * dz;
        bool lt = dd < best;
        best = lt ? dd : best;
        bi = lt ? j : bi;
    }
    out[t] = bi;
}

// ---------------------------------------------------------------- fuse: bf16 GEMM input + fp32 feat output
__global__ void fuse_bf_kernel(const float* __restrict__ fm0, const float* __restrict__ fm1,
                               const float* __restrict__ fm2, const float* __restrict__ fm3,
                               const float* __restrict__ fm4, const float* __restrict__ fg,
                               const float* __restrict__ onehot,
                               const int* __restrict__ n1, const int* __restrict__ n2,
                               ushort* __restrict__ fuse_b, float* __restrict__ feat) {
    long i = blockIdx.x * 256L + threadIdx.x;
    if (i >= 8192L * 1824) return;
    int c = (int)(i % 1824);
    long row = i / 1824;
    int b = (int)(row / VN);
    float val = 0.f;
    if (c < 128)       val = fm0[row * 128 + c];
    else if (c < 256)  val = fm1[row * 128 + (c - 128)];
    else if (c < 512)  val = fm2[((long)b * 512 + n1[row]) * 256 + (c - 256)];
    else if (c < 768)  val = fm3[((long)b * 512 + n1[row]) * 256 + (c - 512)];
    else if (c < 1280) val = fm4[((long)b * 128 + n2[row]) * 512 + (c - 768)];
    else if (c < 1792) val = fg[b * 512 + (c - 1280)];
    else if (c < 1808) val = onehot[b * 16 + (c - 1792)];
    fuse_b[i] = f2bf(val);
    if (c < 1280)                   feat[row * 1296 + c] = val;
    else if (c >= 1792 && c < 1808) feat[row * 1296 + (c - 512)] = val;
}

__global__ void pred_scatter_kernel(const float* __restrict__ pred, float* __restrict__ out) {
    long i = blockIdx.x * 256L + threadIdx.x;
    if (i >= 8192L * 30) return;
    int c = (int)(i % 30);
    long row = i / 30;
    float v = pred[i];
    if (c < 6) out[row * 6 + c] = v;
    else       out[49152 + row * 24 + (c - 6)] = v;
}

// ---------------------------------------------------------------- launch

extern "C" void kernel_launch(void* const* d_in, const int* in_sizes, int n_in,
                              void* d_out, int out_size, void* d_ws, size_t ws_size,
                              hipStream_t stream) {
    const float* verts  = (const float*)d_in[0];
    const float* onehot = (const float*)d_in[1];
    const float* dir0 = (const float*)d_in[2];
    const float* w1 = (const float*)d_in[3];
    const float* b1 = (const float*)d_in[4];
    const float* dir1 = (const float*)d_in[5];
    const float* w2 = (const float*)d_in[6];
    const float* b2 = (const float*)d_in[7];
    const float* dir2 = (const float*)d_in[8];
    const float* w3 = (const float*)d_in[9];
    const float* b3 = (const float*)d_in[10];
    const float* dir3 = (const float*)d_in[11];
    const float* w4 = (const float*)d_in[12];
    const float* b4 = (const float*)d_in[13];
    const float* dir4 = (const float*)d_in[14];
    const float* g_bn1 = (const float*)d_in[15];
    const float* be_bn1 = (const float*)d_in[16];
    const float* g_bn2 = (const float*)d_in[17];
    const float* be_bn2 = (const float*)d_in[18];
    const float* g_bn3 = (const float*)d_in[19];
    const float* be_bn3 = (const float*)d_in[20];
    const float* wc1 = (const float*)d_in[21];
    const float* bc1 = (const float*)d_in[22];
    const float* wc2 = (const float*)d_in[23];
    const float* bc2 = (const float*)d_in[24];
    const float* wc3 = (const float*)d_in[25];
    const float* bc3 = (const float*)d_in[26];
    float* outf = (float*)d_out;

    float* wsf = (float*)d_ws;
    size_t off = 0;
    auto alloc = [&](size_t n) { float* p = wsf + off; off += (n + 15) & ~(size_t)15; return p; };

    float* sd0 = alloc(3 * 896);
    float* sd1 = alloc(3 * 896);
    float* sd2 = alloc(3 * 1792);
    float* sd3 = alloc(3 * 1792);
    float* sd4 = alloc(3 * 3584);
    float* wc3t = alloc(512L * 30);
    float* fm0 = alloc(8192L * 128);
    float* fm1 = alloc(8192L * 128);
    float* c1  = alloc(8192L * 128);
    float* fp1 = alloc(2048L * 128);
    float* fm2 = alloc(2048L * 256);
    float* c2  = alloc(2048L * 256);
    float* fm3 = alloc(2048L * 256);
    float* c3  = alloc(2048L * 256);
    float* fp2 = alloc(512L * 256);
    float* fm4 = alloc(512L * 512);
    float* fg  = alloc(BSZ * 512);
    float* fbuf = alloc(8192L * 1024);   // fo scratch (max 8192x1024)
    float* h2 = alloc(8192L * 512);
    float* pred = alloc(8192L * 30);
    float* bnstat = alloc(512);
    float* pd  = alloc(8192L * 8 * KNB);
    int* pi    = (int*)alloc(8192L * 8 * KNB);
    int* nb   = (int*)alloc(8192L * KNB);
    int* nb1  = (int*)alloc(2048L * KNB);
    int* nb2  = (int*)alloc(512L * KNB);
    int* nbp1 = (int*)alloc(2048L * 4);
    int* nbp2 = (int*)alloc(512L * 4);
    int* n1   = (int*)alloc(8192);
    int* n2   = (int*)alloc(8192);
    ushort* fuse_b = (ushort*)alloc(8192L * 1824 / 2);  // bf16 fuse, K padded to 1824
    ushort* h1b    = (ushort*)alloc(8192L * 512 / 2);
    ushort* wc1b   = (ushort*)alloc(512L * 1824 / 2);
    ushort* wc2b   = (ushort*)alloc(512L * 512 / 2);

    auto nblk = [](long n, int b) { return (unsigned)((n + b - 1) / b); };

    norm_dirs_kernel<<<nblk(896, 256), 256, 0, stream>>>(dir0, sd0, 896);
    norm_dirs_kernel<<<nblk(896, 256), 256, 0, stream>>>(dir1, sd1, 896);
    norm_dirs_kernel<<<nblk(1792, 256), 256, 0, stream>>>(dir2, sd2, 1792);
    norm_dirs_kernel<<<nblk(1792, 256), 256, 0, stream>>>(dir3, sd3, 1792);
    norm_dirs_kernel<<<nblk(3584, 256), 256, 0, stream>>>(dir4, sd4, 3584);
    transpose_kernel<<<nblk(30L * 512, 256), 256, 0, stream>>>(wc3, wc3t, 30, 512);
    // head weights -> bf16 (N,K) layout; wc1/wc2 are already (out,in)=(N,K)
    f2b_pad_kernel<<<nblk(512L * 1824, 256), 256, 0, stream>>>(wc1, wc1b, 512, 1808, 1824);
    f2b_pad_kernel<<<nblk(512L * 512, 256), 256, 0, stream>>>(wc2, wc2b, 512, 512, 512);

    // ---- knn graphs ----
    knn_part_kernel<10><<<dim3(8, BSZ * 8), 256, 3 * 256 * 4, stream>>>(verts, 2048, 2048, 8, pd, pi);
    knn_merge_kernel<10><<<nblk(BSZ * 2048, 256), 256, 0, stream>>>(pd, pi, 2048, 8, nb);
    knn_part_kernel<10><<<dim3(2, BSZ * 4), 256, 3 * 128 * 4, stream>>>(verts, 512, 512, 4, pd, pi);
    knn_merge_kernel<10><<<nblk(BSZ * 512, 256), 256, 0, stream>>>(pd, pi, 512, 4, nb1);
    knn_part_kernel<10><<<dim3(1, BSZ * 1), 128, 3 * 128 * 4, stream>>>(verts, 128, 128, 1, pd, pi);
    knn_merge_kernel<10><<<nblk(BSZ * 128, 128), 128, 0, stream>>>(pd, pi, 128, 1, nb2);
    knn_part_kernel<4><<<dim3(2, BSZ * 8), 256, 3 * 256 * 4, stream>>>(verts, 2048, 512, 8, pd, pi);
    knn_merge_kernel<4><<<nblk(BSZ * 512, 256), 256, 0, stream>>>(pd, pi, 512, 8, nbp1);
    knn_part_kernel<4><<<dim3(1, BSZ * 4), 128, 3 * 128 * 4, stream>>>(verts, 512, 128, 4, pd, pi);
    knn_merge_kernel<4><<<nblk(BSZ * 128, 128), 128, 0, stream>>>(pd, pi, 128, 4, nbp2);

    // fm0
    conv_surface_kernel<<<BSZ * 2048, 128, 0, stream>>>(verts, nb, sd0, fm0);

    // layer1
    gemm_kernel<<<dim3(16, 128), 256, 0, stream>>>(fm0, w1, b1, fbuf, 8192, 128, 1024, 0);
    conv_act_kernel<<<BSZ * 2048, 128, 0, stream>>>(verts, nb, sd1, fbuf, c1, 2048, 128);
    hipMemsetAsync(bnstat, 0, 2 * 128 * sizeof(float), stream);
    bn_stat_kernel<<<32, 128, 0, stream>>>(c1, bnstat, 8192, 128);
    bn_apply_relu_kernel<<<nblk(8192L * 128, 256), 256, 0, stream>>>(c1, bnstat, g_bn1, be_bn1, fm1, 8192, 128);

    // pool1
    pool_kernel<<<nblk(BSZ * 512L * 128, 256), 256, 0, stream>>>(fm1, nbp1, fp1, 2048, 512, 128);

    // layer2
    gemm_kernel<<<dim3(32, 32), 256, 0, stream>>>(fp1, w2, b2, fbuf, 2048, 128, 2048, 0);
    conv_act_kernel<<<BSZ * 512, 256, 0, stream>>>(verts, nb1, sd2, fbuf, c2, 512, 256);
    hipMemsetAsync(bnstat, 0, 2 * 256 * sizeof(float), stream);
    bn_stat_kernel<<<32, 256, 0, stream>>>(c2, bnstat, 2048, 256);
    bn_apply_relu_kernel<<<nblk(2048L * 256, 256), 256, 0, stream>>>(c2, bnstat, g_bn2, be_bn2, fm2, 2048, 256);

    // layer3
    gemm_kernel<<<dim3(32, 32), 256, 0, stream>>>(fm2, w3, b3, fbuf, 2048, 256, 2048, 0);
    conv_act_kernel<<<BSZ * 512, 256, 0, stream>>>(verts, nb1, sd3, fbuf, c3, 512, 256);
    hipMemsetAsync(bnstat, 0, 2 * 256 * sizeof(float), stream);
    bn_stat_kernel<<<32, 256, 0, stream>>>(c3, bnstat, 2048, 256);
    bn_apply_relu_kernel<<<nblk(2048L * 256, 256), 256, 0, stream>>>(c3, bnstat, g_bn3, be_bn3, fm3, 2048, 256);

    // pool2
    pool_kernel<<<nblk(BSZ * 128L * 256, 256), 256, 0, stream>>>(fm3, nbp2, fp2, 512, 128, 256);

    // layer4
    gemm_kernel<<<dim3(64, 8), 256, 0, stream>>>(fp2, w4, b4, fbuf, 512, 256, 4096, 0);
    conv_act_kernel<<<BSZ * 128, 512, 0, stream>>>(verts, nb2, sd4, fbuf, fm4, 128, 512);

    // global max + upsample indices
    fglob_kernel<<<nblk(BSZ * 512, 256), 256, 0, stream>>>(fm4, fg);
    nearest_kernel<<<nblk(BSZ * VN, 256), 256, 3 * 512 * 4, stream>>>(verts, 512, n1);
    nearest_kernel<<<nblk(BSZ * VN, 256), 256, 3 * 128 * 4, stream>>>(verts, 128, n2);

    // fuse -> bf16 GEMM input + fp32 feat (direct to d_out)
    fuse_bf_kernel<<<nblk(8192L * 1824, 256), 256, 0, stream>>>(fm0, fm1, fm2, fm3, fm4, fg, onehot,
                                                                n1, n2, fuse_b, outf + 245760);

    // MLP head: bf16 MFMA for the two big GEMMs, fp32 for the N=30 tail
    gemm_mfma_bt_kernel<<<dim3(4, 64), 256, 0, stream>>>(fuse_b, wc1b, bc1, nullptr, h1b, 8192, 512, 1824, 1);
    gemm_mfma_bt_kernel<<<dim3(4, 64), 256, 0, stream>>>(h1b, wc2b, bc2, h2, nullptr, 8192, 512, 512, 1);
    gemm_kernel<<<dim3(1, 128), 256, 0, stream>>>(h2, wc3t, bc3, pred, 8192, 512, 30, 0);
    pred_scatter_kernel<<<nblk(8192L * 30, 256), 256, 0, stream>>>(pred, outf);
}

// Round 4
// 643.141 us; speedup vs baseline: 4.2348x; 1.7255x over previous
//
#include <hip/hip_runtime.h>
#include <hip/hip_bf16.h>
#include <math.h>

#define BSZ 4
#define VN 2048
#define SS 7
#define KNB 10

typedef __attribute__((ext_vector_type(8))) short short8;
typedef __attribute__((ext_vector_type(4))) float f32x4;

__device__ inline ushort f2bf(float x) {
    __hip_bfloat16 h = __float2bfloat16(x);
    return *(ushort*)&h;
}

// ---------------------------------------------------------------- small prep kernels

// normalize all 5 direction matrices in one launch (total cols 8960)
__global__ void norm_dirs_all(const float* __restrict__ d0, const float* __restrict__ d1,
                              const float* __restrict__ d2, const float* __restrict__ d3,
                              const float* __restrict__ d4,
                              float* __restrict__ s0, float* __restrict__ s1,
                              float* __restrict__ s2, float* __restrict__ s3,
                              float* __restrict__ s4) {
    int i = blockIdx.x * 256 + threadIdx.x;
    const float* src; float* dst; int C, c;
    if (i < 896)        { src = d0; dst = s0; C = 896;  c = i; }
    else if (i < 1792)  { src = d1; dst = s1; C = 896;  c = i - 896; }
    else if (i < 3584)  { src = d2; dst = s2; C = 1792; c = i - 1792; }
    else if (i < 5376)  { src = d3; dst = s3; C = 1792; c = i - 3584; }
    else if (i < 8960)  { src = d4; dst = s4; C = 3584; c = i - 5376; }
    else return;
    float a = src[c], b = src[C + c], e = src[2 * C + c];
    float den = fmaxf(sqrtf(a * a + b * b + e * e), 1e-12f);
    dst[c] = a / den; dst[C + c] = b / den; dst[2 * C + c] = e / den;
}

// (O, Cin) row-major -> (Cin, O) row-major (fp32, for wc3)
__global__ void transpose_kernel(const float* __restrict__ w, float* __restrict__ wt, int O, int Cin) {
    long i = blockIdx.x * 256L + threadIdx.x;
    if (i >= (long)O * Cin) return;
    int o = (int)(i / Cin), c = (int)(i % Cin);
    wt[(long)c * O + o] = w[i];
}

// fp32 (rows,cin) -> bf16 (rows,cpad), zero pad
__global__ void f2b_pad_kernel(const float* __restrict__ src, ushort* __restrict__ dst,
                               long rows, int cin, int cpad) {
    long i = blockIdx.x * 256L + threadIdx.x;
    if (i >= rows * cpad) return;
    int c = (int)(i % cpad);
    long r = i / cpad;
    float v = (c < cin) ? src[r * cin + c] : 0.f;
    dst[i] = f2bf(v);
}

// layer weights (K,N) fp32 -> (N,K) bf16, all 4 in one launch
__global__ void wt_f2b_all(const float* __restrict__ w1, const float* __restrict__ w2,
                           const float* __restrict__ w3, const float* __restrict__ w4,
                           ushort* __restrict__ o1, ushort* __restrict__ o2,
                           ushort* __restrict__ o3, ushort* __restrict__ o4) {
    long i = blockIdx.x * 256L + threadIdx.x;
    const float* w; ushort* o; int K, N; long j;
    if (i < 131072)       { w = w1; o = o1; K = 128; N = 1024; j = i; }
    else if (i < 393216)  { w = w2; o = o2; K = 128; N = 2048; j = i - 131072; }
    else if (i < 917504)  { w = w3; o = o3; K = 256; N = 2048; j = i - 393216; }
    else if (i < 1966080) { w = w4; o = o4; K = 256; N = 4096; j = i - 917504; }
    else return;
    int n = (int)(j / K), k = (int)(j % K);
    o[j] = f2bf(w[(long)k * N + n]);
}

// ---------------------------------------------------------------- knn uber (split-source, branchless insert)
// pd/pi element offsets per segment (floats):
#define KOFF0 0L
#define KOFF1 1310720L   // + 4*2048*16*10
#define KOFF2 1392640L   // + 4*512*4*10
#define KOFF3 1397760L   // + 4*128*1*10
#define KOFF4 1528832L   // + 4*512*16*4
#define KTOT  1537024L   // + 4*128*4*4

template <int KK>
__device__ void knn_part_dev(const float* __restrict__ verts, int Nsrc, int T, int nch,
                             int tile, int b, int ch,
                             float* __restrict__ pd, int* __restrict__ pi,
                             float* sx, float* sy, float* sz) {
    int len = Nsrc / nch;           // always 128 here
    const float* vb = verts + (long)b * VN * 3;
    int j0 = ch * len;
    for (int j = threadIdx.x; j < len; j += 256) {
        sx[j] = vb[(j0 + j) * 3 + 0];
        sy[j] = vb[(j0 + j) * 3 + 1];
        sz[j] = vb[(j0 + j) * 3 + 2];
    }
    __syncthreads();
    int i = tile * 256 + threadIdx.x;
    if (i >= T) return;
    float px = vb[i * 3], py = vb[i * 3 + 1], pz = vb[i * 3 + 2];
    float d[KK]; int id[KK];
#pragma unroll
    for (int q = 0; q < KK; q++) { d[q] = 1e30f; id[q] = 0; }
    for (int j = 0; j < len; j++) {
        float dx = sx[j] - px, dy = sy[j] - py, dz = sz[j] - pz;
        float dd = dx * dx + dy * dy + dz * dz;
        int jj = j0 + j;
        dd = (jj == i) ? 1e30f : dd;   // self-exclude
#pragma unroll
        for (int q = 0; q < KK; q++) {  // branchless sorted insert
            bool lt = dd < d[q];
            float dmin = lt ? dd : d[q];
            float dmax = lt ? d[q] : dd;
            int imin = lt ? jj : id[q];
            int imax = lt ? id[q] : jj;
            d[q] = dmin; id[q] = imin; dd = dmax; jj = imax;
        }
    }
    long base = (((long)b * T + i) * nch + ch) * KK;
#pragma unroll
    for (int q = 0; q < KK; q++) { pd[base + q] = d[q]; pi[base + q] = id[q]; }
}

__global__ __launch_bounds__(256) void knn_part_uber(const float* __restrict__ verts,
                                                     float* __restrict__ pd, int* __restrict__ pi) {
    __shared__ float sx[128], sy[128], sz[128];
    int gb = blockIdx.x;
    if (gb < 512) {            // cfg0: K=10 Nsrc=2048 T=2048 nch=16 tb=8
        int local = gb, tile = local % 8, bc = local / 8;
        knn_part_dev<10>(verts, 2048, 2048, 16, tile, bc / 16, bc % 16, pd + KOFF0, pi + KOFF0, sx, sy, sz);
    } else if (gb < 544) {     // cfg1: K=10 Nsrc=512 T=512 nch=4 tb=2
        int local = gb - 512, tile = local % 2, bc = local / 2;
        knn_part_dev<10>(verts, 512, 512, 4, tile, bc / 4, bc % 4, pd + KOFF1, pi + KOFF1, sx, sy, sz);
    } else if (gb < 548) {     // cfg2: K=10 Nsrc=128 T=128 nch=1 tb=1
        int bc = gb - 544;
        knn_part_dev<10>(verts, 128, 128, 1, 0, bc, 0, pd + KOFF2, pi + KOFF2, sx, sy, sz);
    } else if (gb < 676) {     // cfg3: K=4 Nsrc=2048 T=512 nch=16 tb=2
        int local = gb - 548, tile = local % 2, bc = local / 2;
        knn_part_dev<4>(verts, 2048, 512, 16, tile, bc / 16, bc % 16, pd + KOFF3, pi + KOFF3, sx, sy, sz);
    } else {                   // cfg4: K=4 Nsrc=512 T=128 nch=4 tb=1
        int bc = gb - 676;
        knn_part_dev<4>(verts, 512, 128, 4, 0, bc / 4, bc % 4, pd + KOFF4, pi + KOFF4, sx, sy, sz);
    }
}

template <int KK, int NCH>
__device__ void knn_merge_dev(const float* __restrict__ pd, const int* __restrict__ pi,
                              int t, int* __restrict__ out) {
    float d[KK]; int id[KK];
#pragma unroll
    for (int q = 0; q < KK; q++) { d[q] = 1e30f; id[q] = 0; }
    for (int c = 0; c < NCH; c++) {
        long base = ((long)t * NCH + c) * KK;
        for (int q = 0; q < KK; q++) {
            float dd = pd[base + q];
            if (dd >= d[KK - 1]) break;     // partial lists sorted ascending
            int jj = pi[base + q];
#pragma unroll
            for (int p = 0; p < KK; p++) {
                bool lt = dd < d[p];
                float dmin = lt ? dd : d[p];
                float dmax = lt ? d[p] : dd;
                int imin = lt ? jj : id[p];
                int imax = lt ? id[p] : jj;
                d[p] = dmin; id[p] = imin; dd = dmax; jj = imax;
            }
        }
    }
#pragma unroll
    for (int q = 0; q < KK; q++) out[(long)t * KK + q] = id[q];
}

__global__ void knn_merge_uber(const float* __restrict__ pd, const int* __restrict__ pi,
                               int* __restrict__ nb, int* __restrict__ nb1, int* __restrict__ nb2,
                               int* __restrict__ nbp1, int* __restrict__ nbp2) {
    int gt = blockIdx.x * 256 + threadIdx.x;
    if (gt < 8192)       knn_merge_dev<10, 16>(pd + KOFF0, pi + KOFF0, gt, nb);
    else if (gt < 10240) knn_merge_dev<10, 4>(pd + KOFF1, pi + KOFF1, gt - 8192, nb1);
    else if (gt < 10752) knn_merge_dev<10, 1>(pd + KOFF2, pi + KOFF2, gt - 10240, nb2);
    else if (gt < 12800) knn_merge_dev<4, 16>(pd + KOFF3, pi + KOFF3, gt - 10752, nbp1);
    else                 knn_merge_dev<4, 4>(pd + KOFF4, pi + KOFF4, gt - 12800, nbp2);
}

// ---------------------------------------------------------------- conv_surface (fp32 + bf16 out)
__global__ void conv_surface_kernel(const float* __restrict__ verts, const int* __restrict__ nb,
                                    const float* __restrict__ sd, float* __restrict__ fm0,
                                    ushort* __restrict__ fm0b) {
    int bv = blockIdx.x;
    int b = bv / VN, v = bv % VN;
    __shared__ float snd[KNB][3];
    int tid = threadIdx.x;
    if (tid < KNB) {
        int nj = nb[(long)bv * KNB + tid];
        const float* vb = verts + (long)b * VN * 3;
        float dx = vb[nj * 3] - vb[v * 3];
        float dy = vb[nj * 3 + 1] - vb[v * 3 + 1];
        float dz = vb[nj * 3 + 2] - vb[v * 3 + 2];
        float den = fmaxf(sqrtf(dx * dx + dy * dy + dz * dz), 1e-12f);
        snd[tid][0] = dx / den; snd[tid][1] = dy / den; snd[tid][2] = dz / den;
    }
    __syncthreads();
    int c = tid;
    float acc = 0.f;
    for (int s = 0; s < SS; s++) {
        int col = s * 128 + c;
        float s0 = sd[col], s1 = sd[896 + col], s2 = sd[2 * 896 + col];
        float m = 0.f;
#pragma unroll
        for (int n = 0; n < KNB; n++) {
            float dot = snd[n][0] * s0 + snd[n][1] * s1 + snd[n][2] * s2;
            m = fmaxf(m, dot);
        }
        acc += m;
    }
    fm0[(long)bv * 128 + c] = acc;
    fm0b[(long)bv * 128 + c] = f2bf(acc);
}

// ---------------------------------------------------------------- conv_layer act
__global__ void conv_act_kernel(const float* __restrict__ verts, const int* __restrict__ nb,
                                const float* __restrict__ sd, const float* __restrict__ fo,
                                float* __restrict__ out, int Vl, int outC) {
    int bv = blockIdx.x;
    int b = bv / Vl, v = bv % Vl;
    __shared__ float snd[KNB][3];
    __shared__ int srow[KNB];
    int tid = threadIdx.x;
    if (tid < KNB) {
        int nj = nb[(long)bv * KNB + tid];
        srow[tid] = b * Vl + nj;
        const float* vb = verts + (long)b * VN * 3;
        float dx = vb[nj * 3] - vb[v * 3];
        float dy = vb[nj * 3 + 1] - vb[v * 3 + 1];
        float dz = vb[nj * 3 + 2] - vb[v * 3 + 2];
        float den = fmaxf(sqrtf(dx * dx + dy * dy + dz * dz), 1e-12f);
        snd[tid][0] = dx / den; snd[tid][1] = dy / den; snd[tid][2] = dz / den;
    }
    __syncthreads();
    int c = tid;
    int SC = SS * outC;
    int foN = SC + outC;
    float acc = fo[(long)bv * foN + c];  // center
    for (int s = 0; s < SS; s++) {
        int col = s * outC + c;
        float s0 = sd[col], s1 = sd[SC + col], s2 = sd[2 * SC + col];
        float m = -1e30f;
#pragma unroll
        for (int n = 0; n < KNB; n++) {
            float dot = snd[n][0] * s0 + snd[n][1] * s1 + snd[n][2] * s2;
            float th = fmaxf(dot, 0.f);
            float sup = fo[(long)srow[n] * foN + outC + col];
            m = fmaxf(m, th * sup);
        }
        acc += m;
    }
    out[(long)bv * outC + c] = acc;
}

// ---------------------------------------------------------------- batchnorm
__global__ void bn_stat_kernel(const float* __restrict__ x, float* __restrict__ stat, int R, int C) {
    int c = threadIdx.x;
    int chunk = (R + gridDim.x - 1) / gridDim.x;
    int r0 = blockIdx.x * chunk;
    int r1 = min(r0 + chunk, R);
    float s = 0.f, s2 = 0.f;
    for (int r = r0; r < r1; r++) {
        float v = x[(long)r * C + c];
        s += v; s2 += v * v;
    }
    atomicAdd(&stat[c], s);
    atomicAdd(&stat[C + c], s2);
}

__global__ void bn_apply_relu_kernel(const float* __restrict__ x, const float* __restrict__ stat,
                                     const float* __restrict__ g, const float* __restrict__ be,
                                     float* __restrict__ out, ushort* __restrict__ outb, int R, int C) {
    long i = blockIdx.x * 256L + threadIdx.x;
    if (i >= (long)R * C) return;
    int c = (int)(i % C);
    float mu = stat[c] / R;
    float var = stat[C + c] / R - mu * mu;
    var = fmaxf(var, 0.f);
    float y = (x[i] - mu) * rsqrtf(var + 1e-5f) * g[c] + be[c];
    y = fmaxf(y, 0.f);
    out[i] = y;
    if (outb) outb[i] = f2bf(y);
}

// ---------------------------------------------------------------- pool (max over 4 nbrs) -> bf16
__global__ void pool_b_kernel(const float* __restrict__ fm, const int* __restrict__ idx,
                              ushort* __restrict__ out, int Vin, int T, int C) {
    long i = blockIdx.x * 256L + threadIdx.x;
    if (i >= (long)BSZ * T * C) return;
    int c = (int)(i % C);
    long bt = i / C;
    int b = (int)(bt / T), t = (int)(bt % T);
    const int* id = idx + ((long)b * T + t) * 4;
    float m = -1e30f;
#pragma unroll
    for (int n = 0; n < 4; n++)
        m = fmaxf(m, fm[((long)b * Vin + id[n]) * C + c]);
    out[i] = f2bf(m);
}

// ---------------------------------------------------------------- fp32 GEMM (wc3 head only)
__global__ __launch_bounds__(256) void gemm_kernel(const float* __restrict__ A, const float* __restrict__ B,
                                                   const float* __restrict__ bias, float* __restrict__ C,
                                                   int M, int K, int N, int do_relu) {
    __shared__ float As[16][68];
    __shared__ float Bs[16][68];
    int tid = threadIdx.x;
    int tx = tid % 16, ty = tid / 16;
    int m0 = blockIdx.y * 64, n0 = blockIdx.x * 64;
    float acc[4][4] = {};
    int aRow = tid / 4;
    int aK = (tid % 4) * 4;
    int bK = tid / 16;
    int bN = (tid % 16) * 4;
    bool nfull = (n0 + 64 <= N) && ((N & 3) == 0);
    for (int k0 = 0; k0 < K; k0 += 16) {
        float4 av = *(const float4*)(A + (long)(m0 + aRow) * K + k0 + aK);
        As[aK + 0][aRow] = av.x; As[aK + 1][aRow] = av.y;
        As[aK + 2][aRow] = av.z; As[aK + 3][aRow] = av.w;
        if (nfull) {
            float4 bv = *(const float4*)(B + (long)(k0 + bK) * N + n0 + bN);
            Bs[bK][bN] = bv.x; Bs[bK][bN + 1] = bv.y; Bs[bK][bN + 2] = bv.z; Bs[bK][bN + 3] = bv.w;
        } else {
#pragma unroll
            for (int j = 0; j < 4; j++) {
                int n = n0 + bN + j;
                Bs[bK][bN + j] = (n < N) ? B[(long)(k0 + bK) * N + n] : 0.f;
            }
        }
        __syncthreads();
#pragma unroll
        for (int kk = 0; kk < 16; kk++) {
            float4 a4 = *(const float4*)&As[kk][ty * 4];
            float4 b4 = *(const float4*)&Bs[kk][tx * 4];
            float a[4] = {a4.x, a4.y, a4.z, a4.w};
            float bb[4] = {b4.x, b4.y, b4.z, b4.w};
#pragma unroll
            for (int ii = 0; ii < 4; ii++)
#pragma unroll
                for (int jj = 0; jj < 4; jj++)
                    acc[ii][jj] += a[ii] * bb[jj];
        }
        __syncthreads();
    }
#pragma unroll
    for (int ii = 0; ii < 4; ii++) {
        int m = m0 + ty * 4 + ii;
#pragma unroll
        for (int jj = 0; jj < 4; jj++) {
            int n = n0 + tx * 4 + jj;
            if (n < N) {
                float v = acc[ii][jj] + bias[n];
                if (do_relu) v = fmaxf(v, 0.f);
                C[(long)m * N + n] = v;
            }
        }
    }
}

// ---------------------------------------------------------------- bf16 MFMA GEMM (Bt = (N,K))
__global__ __launch_bounds__(256) void gemm_mfma_bt_kernel(
    const ushort* __restrict__ A, const ushort* __restrict__ Bt,
    const float* __restrict__ bias, float* __restrict__ Cf, ushort* __restrict__ Cb,
    int M, int N, int K, int relu)
{
    __shared__ ushort As[128 * 32];
    __shared__ ushort Bs[128 * 32];
    int t = threadIdx.x;
    int w = t >> 6, l = t & 63;
    int quad = l >> 4, lm = l & 15;
    int wm = w >> 1, wn = w & 1;
    long m0 = blockIdx.y * 128L;
    long n0 = blockIdx.x * 128L;
    int lr = t >> 2;
    int lk = (t & 3) * 8;
    f32x4 acc[4][4];
#pragma unroll
    for (int i = 0; i < 4; i++)
#pragma unroll
        for (int j = 0; j < 4; j++) acc[i][j] = (f32x4){0.f, 0.f, 0.f, 0.f};

    for (int k0 = 0; k0 < K; k0 += 32) {
        uint4 a0 = *(const uint4*)(A + (m0 + lr) * K + k0 + lk);
        uint4 a1 = *(const uint4*)(A + (m0 + 64 + lr) * K + k0 + lk);
        uint4 b0 = *(const uint4*)(Bt + (n0 + lr) * K + k0 + lk);
        uint4 b1 = *(const uint4*)(Bt + (n0 + 64 + lr) * K + k0 + lk);
        __syncthreads();
        *(uint4*)&As[lr * 32 + lk] = a0;
        *(uint4*)&As[(64 + lr) * 32 + lk] = a1;
        *(uint4*)&Bs[lr * 32 + lk] = b0;
        *(uint4*)&Bs[(64 + lr) * 32 + lk] = b1;
        __syncthreads();
        short8 af[4], bfr[4];
#pragma unroll
        for (int i = 0; i < 4; i++)
            af[i] = *(const short8*)&As[(wm * 64 + i * 16 + lm) * 32 + quad * 8];
#pragma unroll
        for (int j = 0; j < 4; j++)
            bfr[j] = *(const short8*)&Bs[(wn * 64 + j * 16 + lm) * 32 + quad * 8];
#pragma unroll
        for (int i = 0; i < 4; i++)
#pragma unroll
            for (int j = 0; j < 4; j++)
                acc[i][j] = __builtin_amdgcn_mfma_f32_16x16x32_bf16(af[i], bfr[j], acc[i][j], 0, 0, 0);
    }
#pragma unroll
    for (int i = 0; i < 4; i++) {
#pragma unroll
        for (int j = 0; j < 4; j++) {
            int n = (int)n0 + wn * 64 + j * 16 + lm;
            float bv = bias[n];
#pragma unroll
            for (int r = 0; r < 4; r++) {
                int m = (int)m0 + wm * 64 + i * 16 + quad * 4 + r;
                float v = acc[i][j][r] + bv;
                if (relu) v = fmaxf(v, 0.f);
                if (Cf) Cf[(long)m * N + n] = v;
                if (Cb) Cb[(long)m * N + n] = f2bf(v);
            }
        }
    }
}

// ---------------------------------------------------------------- global max over 128 rows
__global__ void fglob_kernel(const float* __restrict__ fm4, float* __restrict__ fg) {
    int t = blockIdx.x * blockDim.x + threadIdx.x;
    if (t >= BSZ * 512) return;
    int b = t / 512, c = t % 512;
    float m = -1e30f;
    for (int r = 0; r < 128; r++)
        m = fmaxf(m, fm4[((long)b * 128 + r) * 512 + c]);
    fg[t] = m;
}

// ---------------------------------------------------------------- nearest (both SN=512 and SN=128)
__global__ void nearest_both_kernel(const float* __restrict__ verts, int* __restrict__ n1,
                                    int* __restrict__ n2) {
    __shared__ float sx[512], sy[512], sz[512];
    int gb = blockIdx.x;
    int SN = (gb < 32) ? 512 : 128;
    int* out = (gb < 32) ? n1 : n2;
    int t = (gb & 31) * 256 + threadIdx.x;  // 0..8191
    int b = t / VN;
    const float* vb = verts + (long)b * VN * 3;
    for (int j = threadIdx.x; j < SN; j += 256) {
        sx[j] = vb[j * 3]; sy[j] = vb[j * 3 + 1]; sz[j] = vb[j * 3 + 2];
    }
    __syncthreads();
    int i = t % VN;
    float px = vb[i * 3], py = vb[i * 3 + 1], pz = vb[i * 3 + 2];
    float best = 1e30f; int bi = 0;
    for (int j = 0; j < SN; j++) {
        float dx = sx[j] - px, dy = sy[j] - py, dz = sz[j] - pz;
        float dd = dx * dx + dy * dy + dz * dz;
        bool lt = dd < best;
        best = lt ? dd : best;
        bi = lt ? j : bi;
    }
    out[t] = bi;
}

// ---------------------------------------------------------------- fuse: bf16 GEMM input + fp32 feat output
__global__ void fuse_bf_kernel(const float* __restrict__ fm0, const float* __restrict__ fm1,
                               const float* __restrict__ fm2, const float* __restrict__ fm3,
                               const float* __restrict__ fm4, const float* __restrict__ fg,
                               const float* __restrict__ onehot,
                               const int* __restrict__ n1, const int* __restrict__ n2,
                               ushort* __restrict__ fuse_b, float* __restrict__ feat) {
    long i = blockIdx.x * 256L + threadIdx.x;
    if (i >= 8192L * 1824) return;
    int c = (int)(i % 1824);
    long row = i / 1824;
    int b = (int)(row / VN);
    float val = 0.f;
    if (c < 128)       val = fm0[row * 128 + c];
    else if (c < 256)  val = fm1[row * 128 + (c - 128)];
    else if (c < 512)  val = fm2[((long)b * 512 + n1[row]) * 256 + (c - 256)];
    else if (c < 768)  val = fm3[((long)b * 512 + n1[row]) * 256 + (c - 512)];
    else if (c < 1280) val = fm4[((long)b * 128 + n2[row]) * 512 + (c - 768)];
    else if (c < 1792) val = fg[b * 512 + (c - 1280)];
    else if (c < 1808) val = onehot[b * 16 + (c - 1792)];
    fuse_b[i] = f2bf(val);
    if (c < 1280)                   feat[row * 1296 + c] = val;
    else if (c >= 1792 && c < 1808) feat[row * 1296 + (c - 512)] = val;
}

__global__ void pred_scatter_kernel(const float* __restrict__ pred, float* __restrict__ out) {
    long i = blockIdx.x * 256L + threadIdx.x;
    if (i >= 8192L * 30) return;
    int c = (int)(i % 30);
    long row = i / 30;
    float v = pred[i];
    if (c < 6) out[row * 6 + c] = v;
    else       out[49152 + row * 24 + (c - 6)] = v;
}

// ---------------------------------------------------------------- launch

extern "C" void kernel_launch(void* const* d_in, const int* in_sizes, int n_in,
                              void* d_out, int out_size, void* d_ws, size_t ws_size,
                              hipStream_t stream) {
    const float* verts  = (const float*)d_in[0];
    const float* onehot = (const float*)d_in[1];
    const float* dir0 = (const float*)d_in[2];
    const float* w1 = (const float*)d_in[3];
    const float* b1 = (const float*)d_in[4];
    const float* dir1 = (const float*)d_in[5];
    const float* w2 = (const float*)d_in[6];
    const float* b2 = (const float*)d_in[7];
    const float* dir2 = (const float*)d_in[8];
    const float* w3 = (const float*)d_in[9];
    const float* b3 = (const float*)d_in[10];
    const float* dir3 = (const float*)d_in[11];
    const float* w4 = (const float*)d_in[12];
    const float* b4 = (const float*)d_in[13];
    const float* dir4 = (const float*)d_in[14];
    const float* g_bn1 = (const float*)d_in[15];
    const float* be_bn1 = (const float*)d_in[16];
    const float* g_bn2 = (const float*)d_in[17];
    const float* be_bn2 = (const float*)d_in[18];
    const float* g_bn3 = (const float*)d_in[19];
    const float* be_bn3 = (const float*)d_in[20];
    const float* wc1 = (const float*)d_in[21];
    const float* bc1 = (const float*)d_in[22];
    const float* wc2 = (const float*)d_in[23];
    const float* bc2 = (const float*)d_in[24];
    const float* wc3 = (const float*)d_in[25];
    const float* bc3 = (const float*)d_in[26];
    float* outf = (float*)d_out;

    float* wsf = (float*)d_ws;
    size_t off = 0;
    auto alloc = [&](size_t n) { float* p = wsf + off; off += (n + 15) & ~(size_t)15; return p; };

    float* sd0 = alloc(3 * 896);
    float* sd1 = alloc(3 * 896);
    float* sd2 = alloc(3 * 1792);
    float* sd3 = alloc(3 * 1792);
    float* sd4 = alloc(3 * 3584);
    float* wc3t = alloc(512L * 30);
    float* fm0 = alloc(8192L * 128);
    float* fm1 = alloc(8192L * 128);
    float* c1  = alloc(8192L * 128);
    float* fm2 = alloc(2048L * 256);
    float* c2  = alloc(2048L * 256);
    float* fm3 = alloc(2048L * 256);
    float* c3  = alloc(2048L * 256);
    float* fm4 = alloc(512L * 512);
    float* fg  = alloc(BSZ * 512);
    float* fbuf = alloc(8192L * 1024);   // fo scratch (max 8192x1024)
    float* h2 = alloc(8192L * 512);
    float* pred = alloc(8192L * 30);
    float* bnstat = alloc(512);
    float* pd  = alloc(KTOT);
    int* pi    = (int*)alloc(KTOT);
    int* nb   = (int*)alloc(8192L * KNB);
    int* nb1  = (int*)alloc(2048L * KNB);
    int* nb2  = (int*)alloc(512L * KNB);
    int* nbp1 = (int*)alloc(2048L * 4);
    int* nbp2 = (int*)alloc(512L * 4);
    int* n1   = (int*)alloc(8192);
    int* n2   = (int*)alloc(8192);
    ushort* fuse_b = (ushort*)alloc(8192L * 1824 / 2);
    ushort* h1b    = (ushort*)alloc(8192L * 512 / 2);
    ushort* wc1b   = (ushort*)alloc(512L * 1824 / 2);
    ushort* wc2b   = (ushort*)alloc(512L * 512 / 2);
    ushort* w1tb   = (ushort*)alloc(1024L * 128 / 2);
    ushort* w2tb   = (ushort*)alloc(2048L * 128 / 2);
    ushort* w3tb   = (ushort*)alloc(2048L * 256 / 2);
    ushort* w4tb   = (ushort*)alloc(4096L * 256 / 2);
    ushort* fm0b   = (ushort*)alloc(8192L * 128 / 2);
    ushort* fp1b   = (ushort*)alloc(2048L * 128 / 2);
    ushort* fm2b   = (ushort*)alloc(2048L * 256 / 2);
    ushort* fp2b   = (ushort*)alloc(512L * 256 / 2);

    auto nblk = [](long n, int b) { return (unsigned)((n + b - 1) / b); };

    // prep
    norm_dirs_all<<<35, 256, 0, stream>>>(dir0, dir1, dir2, dir3, dir4, sd0, sd1, sd2, sd3, sd4);
    transpose_kernel<<<nblk(30L * 512, 256), 256, 0, stream>>>(wc3, wc3t, 30, 512);
    f2b_pad_kernel<<<nblk(512L * 1824, 256), 256, 0, stream>>>(wc1, wc1b, 512, 1808, 1824);
    f2b_pad_kernel<<<nblk(512L * 512, 256), 256, 0, stream>>>(wc2, wc2b, 512, 512, 512);
    wt_f2b_all<<<7680, 256, 0, stream>>>(w1, w2, w3, w4, w1tb, w2tb, w3tb, w4tb);

    // knn graphs (one part launch + one merge launch)
    knn_part_uber<<<692, 256, 0, stream>>>(verts, pd, pi);
    knn_merge_uber<<<52, 256, 0, stream>>>(pd, pi, nb, nb1, nb2, nbp1, nbp2);

    // fm0
    conv_surface_kernel<<<BSZ * 2048, 128, 0, stream>>>(verts, nb, sd0, fm0, fm0b);

    // layer1 (M=8192, N=1024, K=128)
    gemm_mfma_bt_kernel<<<dim3(8, 64), 256, 0, stream>>>(fm0b, w1tb, b1, fbuf, nullptr, 8192, 1024, 128, 0);
    conv_act_kernel<<<BSZ * 2048, 128, 0, stream>>>(verts, nb, sd1, fbuf, c1, 2048, 128);
    hipMemsetAsync(bnstat, 0, 2 * 128 * sizeof(float), stream);
    bn_stat_kernel<<<32, 128, 0, stream>>>(c1, bnstat, 8192, 128);
    bn_apply_relu_kernel<<<nblk(8192L * 128, 256), 256, 0, stream>>>(c1, bnstat, g_bn1, be_bn1, fm1, nullptr, 8192, 128);

    // pool1 -> bf16
    pool_b_kernel<<<nblk(BSZ * 512L * 128, 256), 256, 0, stream>>>(fm1, nbp1, fp1b, 2048, 512, 128);

    // layer2 (M=2048, N=2048, K=128)
    gemm_mfma_bt_kernel<<<dim3(16, 16), 256, 0, stream>>>(fp1b, w2tb, b2, fbuf, nullptr, 2048, 2048, 128, 0);
    conv_act_kernel<<<BSZ * 512, 256, 0, stream>>>(verts, nb1, sd2, fbuf, c2, 512, 256);
    hipMemsetAsync(bnstat, 0, 2 * 256 * sizeof(float), stream);
    bn_stat_kernel<<<32, 256, 0, stream>>>(c2, bnstat, 2048, 256);
    bn_apply_relu_kernel<<<nblk(2048L * 256, 256), 256, 0, stream>>>(c2, bnstat, g_bn2, be_bn2, fm2, fm2b, 2048, 256);

    // layer3 (M=2048, N=2048, K=256)
    gemm_mfma_bt_kernel<<<dim3(16, 16), 256, 0, stream>>>(fm2b, w3tb, b3, fbuf, nullptr, 2048, 2048, 256, 0);
    conv_act_kernel<<<BSZ * 512, 256, 0, stream>>>(verts, nb1, sd3, fbuf, c3, 512, 256);
    hipMemsetAsync(bnstat, 0, 2 * 256 * sizeof(float), stream);
    bn_stat_kernel<<<32, 256, 0, stream>>>(c3, bnstat, 2048, 256);
    bn_apply_relu_kernel<<<nblk(2048L * 256, 256), 256, 0, stream>>>(c3, bnstat, g_bn3, be_bn3, fm3, nullptr, 2048, 256);

    // pool2 -> bf16
    pool_b_kernel<<<nblk(BSZ * 128L * 256, 256), 256, 0, stream>>>(fm3, nbp2, fp2b, 512, 128, 256);

    // layer4 (M=512, N=4096, K=256)
    gemm_mfma_bt_kernel<<<dim3(32, 4), 256, 0, stream>>>(fp2b, w4tb, b4, fbuf, nullptr, 512, 4096, 256, 0);
    conv_act_kernel<<<BSZ * 128, 512, 0, stream>>>(verts, nb2, sd4, fbuf, fm4, 128, 512);

    // global max + upsample indices
    fglob_kernel<<<nblk(BSZ * 512, 256), 256, 0, stream>>>(fm4, fg);
    nearest_both_kernel<<<64, 256, 0, stream>>>(verts, n1, n2);

    // fuse -> bf16 GEMM input + fp32 feat (direct to d_out)
    fuse_bf_kernel<<<nblk(8192L * 1824, 256), 256, 0, stream>>>(fm0, fm1, fm2, fm3, fm4, fg, onehot,
                                                                n1, n2, fuse_b, outf + 245760);

    // MLP head
    gemm_mfma_bt_kernel<<<dim3(4, 64), 256, 0, stream>>>(fuse_b, wc1b, bc1, nullptr, h1b, 8192, 512, 1824, 1);
    gemm_mfma_bt_kernel<<<dim3(4, 64), 256, 0, stream>>>(h1b, wc2b, bc2, h2, nullptr, 8192, 512, 512, 1);
    gemm_kernel<<<dim3(1, 128), 256, 0, stream>>>(h2, wc3t, bc3, pred, 8192, 512, 30, 0);
    pred_scatter_kernel<<<nblk(8192L * 30, 256), 256, 0, stream>>>(pred, outf);
}

// Round 5
// 565.762 us; speedup vs baseline: 4.8140x; 1.1368x over previous
//
#include <hip/hip_runtime.h>
#include <hip/hip_bf16.h>
#include <math.h>

#define BSZ 4
#define VN 2048
#define SS 7
#define KNB 10

typedef __attribute__((ext_vector_type(8))) short short8;
typedef __attribute__((ext_vector_type(4))) float f32x4;

__device__ inline ushort f2bf(float x) {
    __hip_bfloat16 h = __float2bfloat16(x);
    return *(ushort*)&h;
}

// monotonic float<->uint encoding for atomicMax on floats
__device__ inline unsigned fenc(float f) {
    unsigned b = __float_as_uint(f);
    return (b & 0x80000000u) ? ~b : (b | 0x80000000u);
}
__device__ inline float fdec(unsigned e) {
    unsigned b = (e & 0x80000000u) ? (e & 0x7FFFFFFFu) : ~e;
    return __uint_as_float(b);
}

// ---------------------------------------------------------------- small prep kernels

__global__ void norm_dirs_all(const float* __restrict__ d0, const float* __restrict__ d1,
                              const float* __restrict__ d2, const float* __restrict__ d3,
                              const float* __restrict__ d4,
                              float* __restrict__ s0, float* __restrict__ s1,
                              float* __restrict__ s2, float* __restrict__ s3,
                              float* __restrict__ s4) {
    int i = blockIdx.x * 256 + threadIdx.x;
    const float* src; float* dst; int C, c;
    if (i < 896)        { src = d0; dst = s0; C = 896;  c = i; }
    else if (i < 1792)  { src = d1; dst = s1; C = 896;  c = i - 896; }
    else if (i < 3584)  { src = d2; dst = s2; C = 1792; c = i - 1792; }
    else if (i < 5376)  { src = d3; dst = s3; C = 1792; c = i - 3584; }
    else if (i < 8960)  { src = d4; dst = s4; C = 3584; c = i - 5376; }
    else return;
    float a = src[c], b = src[C + c], e = src[2 * C + c];
    float den = fmaxf(sqrtf(a * a + b * b + e * e), 1e-12f);
    dst[c] = a / den; dst[C + c] = b / den; dst[2 * C + c] = e / den;
}

__global__ void transpose_kernel(const float* __restrict__ w, float* __restrict__ wt, int O, int Cin) {
    long i = blockIdx.x * 256L + threadIdx.x;
    if (i >= (long)O * Cin) return;
    int o = (int)(i / Cin), c = (int)(i % Cin);
    wt[(long)c * O + o] = w[i];
}

__global__ void f2b_pad_kernel(const float* __restrict__ src, ushort* __restrict__ dst,
                               long rows, int cin, int cpad) {
    long i = blockIdx.x * 256L + threadIdx.x;
    if (i >= rows * cpad) return;
    int c = (int)(i % cpad);
    long r = i / cpad;
    float v = (c < cin) ? src[r * cin + c] : 0.f;
    dst[i] = f2bf(v);
}

__global__ void wt_f2b_all(const float* __restrict__ w1, const float* __restrict__ w2,
                           const float* __restrict__ w3, const float* __restrict__ w4,
                           ushort* __restrict__ o1, ushort* __restrict__ o2,
                           ushort* __restrict__ o3, ushort* __restrict__ o4) {
    long i = blockIdx.x * 256L + threadIdx.x;
    const float* w; ushort* o; int K, N; long j;
    if (i < 131072)       { w = w1; o = o1; K = 128; N = 1024; j = i; }
    else if (i < 393216)  { w = w2; o = o2; K = 128; N = 2048; j = i - 131072; }
    else if (i < 917504)  { w = w3; o = o3; K = 256; N = 2048; j = i - 393216; }
    else if (i < 1966080) { w = w4; o = o4; K = 256; N = 4096; j = i - 917504; }
    else return;
    int n = (int)(j / K), k = (int)(j % K);
    o[j] = f2bf(w[(long)k * N + n]);
}

// ---------------------------------------------------------------- knn uber
#define KOFF0 0L
#define KOFF1 1310720L
#define KOFF2 1392640L
#define KOFF3 1397760L
#define KOFF4 1528832L
#define KTOT  1537024L

template <int KK>
__device__ void knn_part_dev(const float* __restrict__ verts, int Nsrc, int T, int nch,
                             int tile, int b, int ch,
                             float* __restrict__ pd, int* __restrict__ pi,
                             float* sx, float* sy, float* sz) {
    int len = Nsrc / nch;
    const float* vb = verts + (long)b * VN * 3;
    int j0 = ch * len;
    for (int j = threadIdx.x; j < len; j += 256) {
        sx[j] = vb[(j0 + j) * 3 + 0];
        sy[j] = vb[(j0 + j) * 3 + 1];
        sz[j] = vb[(j0 + j) * 3 + 2];
    }
    __syncthreads();
    int i = tile * 256 + threadIdx.x;
    if (i >= T) return;
    float px = vb[i * 3], py = vb[i * 3 + 1], pz = vb[i * 3 + 2];
    float d[KK]; int id[KK];
#pragma unroll
    for (int q = 0; q < KK; q++) { d[q] = 1e30f; id[q] = 0; }
    for (int j = 0; j < len; j++) {
        float dx = sx[j] - px, dy = sy[j] - py, dz = sz[j] - pz;
        float dd = dx * dx + dy * dy + dz * dz;
        int jj = j0 + j;
        dd = (jj == i) ? 1e30f : dd;
#pragma unroll
        for (int q = 0; q < KK; q++) {
            bool lt = dd < d[q];
            float dmin = lt ? dd : d[q];
            float dmax = lt ? d[q] : dd;
            int imin = lt ? jj : id[q];
            int imax = lt ? id[q] : jj;
            d[q] = dmin; id[q] = imin; dd = dmax; jj = imax;
        }
    }
    long base = (((long)b * T + i) * nch + ch) * KK;
#pragma unroll
    for (int q = 0; q < KK; q++) { pd[base + q] = d[q]; pi[base + q] = id[q]; }
}

__global__ __launch_bounds__(256) void knn_part_uber(const float* __restrict__ verts,
                                                     float* __restrict__ pd, int* __restrict__ pi) {
    __shared__ float sx[128], sy[128], sz[128];
    int gb = blockIdx.x;
    if (gb < 512) {
        int local = gb, tile = local % 8, bc = local / 8;
        knn_part_dev<10>(verts, 2048, 2048, 16, tile, bc / 16, bc % 16, pd + KOFF0, pi + KOFF0, sx, sy, sz);
    } else if (gb < 544) {
        int local = gb - 512, tile = local % 2, bc = local / 2;
        knn_part_dev<10>(verts, 512, 512, 4, tile, bc / 4, bc % 4, pd + KOFF1, pi + KOFF1, sx, sy, sz);
    } else if (gb < 548) {
        int bc = gb - 544;
        knn_part_dev<10>(verts, 128, 128, 1, 0, bc, 0, pd + KOFF2, pi + KOFF2, sx, sy, sz);
    } else if (gb < 676) {
        int local = gb - 548, tile = local % 2, bc = local / 2;
        knn_part_dev<4>(verts, 2048, 512, 16, tile, bc / 16, bc % 16, pd + KOFF3, pi + KOFF3, sx, sy, sz);
    } else {
        int bc = gb - 676;
        knn_part_dev<4>(verts, 512, 128, 4, 0, bc / 4, bc % 4, pd + KOFF4, pi + KOFF4, sx, sy, sz);
    }
}

template <int KK, int NCH>
__device__ void knn_merge_dev(const float* __restrict__ pd, const int* __restrict__ pi,
                              int t, int* __restrict__ out) {
    float d[KK]; int id[KK];
#pragma unroll
    for (int q = 0; q < KK; q++) { d[q] = 1e30f; id[q] = 0; }
    for (int c = 0; c < NCH; c++) {
        long base = ((long)t * NCH + c) * KK;
        for (int q = 0; q < KK; q++) {
            float dd = pd[base + q];
            if (dd >= d[KK - 1]) break;
            int jj = pi[base + q];
#pragma unroll
            for (int p = 0; p < KK; p++) {
                bool lt = dd < d[p];
                float dmin = lt ? dd : d[p];
                float dmax = lt ? d[p] : dd;
                int imin = lt ? jj : id[p];
                int imax = lt ? id[p] : jj;
                d[p] = dmin; id[p] = imin; dd = dmax; jj = imax;
            }
        }
    }
#pragma unroll
    for (int q = 0; q < KK; q++) out[(long)t * KK + q] = id[q];
}

__global__ void knn_merge_uber(const float* __restrict__ pd, const int* __restrict__ pi,
                               int* __restrict__ nb, int* __restrict__ nb1, int* __restrict__ nb2,
                               int* __restrict__ nbp1, int* __restrict__ nbp2) {
    int gt = blockIdx.x * 256 + threadIdx.x;
    if (gt < 8192)       knn_merge_dev<10, 16>(pd + KOFF0, pi + KOFF0, gt, nb);
    else if (gt < 10240) knn_merge_dev<10, 4>(pd + KOFF1, pi + KOFF1, gt - 8192, nb1);
    else if (gt < 10752) knn_merge_dev<10, 1>(pd + KOFF2, pi + KOFF2, gt - 10240, nb2);
    else if (gt < 12800) knn_merge_dev<4, 16>(pd + KOFF3, pi + KOFF3, gt - 10752, nbp1);
    else                 knn_merge_dev<4, 4>(pd + KOFF4, pi + KOFF4, gt - 12800, nbp2);
}

// ---------------------------------------------------------------- conv_surface (fp32 + bf16 out)
__global__ void conv_surface_kernel(const float* __restrict__ verts, const int* __restrict__ nb,
                                    const float* __restrict__ sd, float* __restrict__ fm0,
                                    ushort* __restrict__ fm0b) {
    int bv = blockIdx.x;
    int b = bv / VN, v = bv % VN;
    __shared__ float snd[KNB][3];
    int tid = threadIdx.x;
    if (tid < KNB) {
        int nj = nb[(long)bv * KNB + tid];
        const float* vb = verts + (long)b * VN * 3;
        float dx = vb[nj * 3] - vb[v * 3];
        float dy = vb[nj * 3 + 1] - vb[v * 3 + 1];
        float dz = vb[nj * 3 + 2] - vb[v * 3 + 2];
        float den = fmaxf(sqrtf(dx * dx + dy * dy + dz * dz), 1e-12f);
        snd[tid][0] = dx / den; snd[tid][1] = dy / den; snd[tid][2] = dz / den;
    }
    __syncthreads();
    int c = tid;
    float acc = 0.f;
    for (int s = 0; s < SS; s++) {
        int col = s * 128 + c;
        float s0 = sd[col], s1 = sd[896 + col], s2 = sd[2 * 896 + col];
        float m = 0.f;
#pragma unroll
        for (int n = 0; n < KNB; n++) {
            float dot = snd[n][0] * s0 + snd[n][1] * s1 + snd[n][2] * s2;
            m = fmaxf(m, dot);
        }
        acc += m;
    }
    fm0[(long)bv * 128 + c] = acc;
    fm0b[(long)bv * 128 + c] = f2bf(acc);
}

// ---------------------------------------------------------------- conv_layer act (+optional fg atomic max)
__global__ void conv_act_kernel(const float* __restrict__ verts, const int* __restrict__ nb,
                                const float* __restrict__ sd, const float* __restrict__ fo,
                                float* __restrict__ out, unsigned* __restrict__ fgmax,
                                int Vl, int outC) {
    int bv = blockIdx.x;
    int b = bv / Vl, v = bv % Vl;
    __shared__ float snd[KNB][3];
    __shared__ int srow[KNB];
    int tid = threadIdx.x;
    if (tid < KNB) {
        int nj = nb[(long)bv * KNB + tid];
        srow[tid] = b * Vl + nj;
        const float* vb = verts + (long)b * VN * 3;
        float dx = vb[nj * 3] - vb[v * 3];
        float dy = vb[nj * 3 + 1] - vb[v * 3 + 1];
        float dz = vb[nj * 3 + 2] - vb[v * 3 + 2];
        float den = fmaxf(sqrtf(dx * dx + dy * dy + dz * dz), 1e-12f);
        snd[tid][0] = dx / den; snd[tid][1] = dy / den; snd[tid][2] = dz / den;
    }
    __syncthreads();
    int c = tid;
    int SC = SS * outC;
    int foN = SC + outC;
    float acc = fo[(long)bv * foN + c];  // center
    for (int s = 0; s < SS; s++) {
        int col = s * outC + c;
        float s0 = sd[col], s1 = sd[SC + col], s2 = sd[2 * SC + col];
        float m = -1e30f;
#pragma unroll
        for (int n = 0; n < KNB; n++) {
            float dot = snd[n][0] * s0 + snd[n][1] * s1 + snd[n][2] * s2;
            float th = fmaxf(dot, 0.f);
            float sup = fo[(long)srow[n] * foN + outC + col];
            m = fmaxf(m, th * sup);
        }
        acc += m;
    }
    out[(long)bv * outC + c] = acc;
    if (fgmax) atomicMax(&fgmax[b * outC + c], fenc(acc));
}

// ---------------------------------------------------------------- batchnorm (parallel stats)
__global__ __launch_bounds__(256) void bn_stat_kernel(const float* __restrict__ x,
                                                      float* __restrict__ stat, int R, int C) {
    int rp = 256 / C;                 // rows in flight per block-iter (2 for C=128, 1 for C=256)
    int c = threadIdx.x % C;
    int rs = threadIdx.x / C;
    float s = 0.f, s2 = 0.f;
    for (long r = (long)blockIdx.x * rp + rs; r < R; r += (long)gridDim.x * rp) {
        float v = x[r * C + c];
        s += v; s2 += v * v;
    }
    atomicAdd(&stat[c], s);
    atomicAdd(&stat[C + c], s2);
}

__global__ void bn_apply_relu_kernel(const float* __restrict__ x, const float* __restrict__ stat,
                                     const float* __restrict__ g, const float* __restrict__ be,
                                     float* __restrict__ out, ushort* __restrict__ outb, int R, int C) {
    long i = blockIdx.x * 256L + threadIdx.x;
    if (i >= (long)R * C) return;
    int c = (int)(i % C);
    float mu = stat[c] / R;
    float var = stat[C + c] / R - mu * mu;
    var = fmaxf(var, 0.f);
    float y = (x[i] - mu) * rsqrtf(var + 1e-5f) * g[c] + be[c];
    y = fmaxf(y, 0.f);
    out[i] = y;
    if (outb) outb[i] = f2bf(y);
}

// ---------------------------------------------------------------- pool (max over 4 nbrs) -> bf16
__global__ void pool_b_kernel(const float* __restrict__ fm, const int* __restrict__ idx,
                              ushort* __restrict__ out, int Vin, int T, int C) {
    long i = blockIdx.x * 256L + threadIdx.x;
    if (i >= (long)BSZ * T * C) return;
    int c = (int)(i % C);
    long bt = i / C;
    int b = (int)(bt / T), t = (int)(bt % T);
    const int* id = idx + ((long)b * T + t) * 4;
    float m = -1e30f;
#pragma unroll
    for (int n = 0; n < 4; n++)
        m = fmaxf(m, fm[((long)b * Vin + id[n]) * C + c]);
    out[i] = f2bf(m);
}

// ---------------------------------------------------------------- fp32 GEMM (wc3 head; scatter epilogue)
__global__ __launch_bounds__(256) void gemm_kernel(const float* __restrict__ A, const float* __restrict__ B,
                                                   const float* __restrict__ bias, float* __restrict__ C,
                                                   int M, int K, int N, int scatter) {
    __shared__ float As[16][68];
    __shared__ float Bs[16][68];
    int tid = threadIdx.x;
    int tx = tid % 16, ty = tid / 16;
    int m0 = blockIdx.y * 64, n0 = blockIdx.x * 64;
    float acc[4][4] = {};
    int aRow = tid / 4;
    int aK = (tid % 4) * 4;
    int bK = tid / 16;
    int bN = (tid % 16) * 4;
    bool nfull = (n0 + 64 <= N) && ((N & 3) == 0);
    for (int k0 = 0; k0 < K; k0 += 16) {
        float4 av = *(const float4*)(A + (long)(m0 + aRow) * K + k0 + aK);
        As[aK + 0][aRow] = av.x; As[aK + 1][aRow] = av.y;
        As[aK + 2][aRow] = av.z; As[aK + 3][aRow] = av.w;
        if (nfull) {
            float4 bv = *(const float4*)(B + (long)(k0 + bK) * N + n0 + bN);
            Bs[bK][bN] = bv.x; Bs[bK][bN + 1] = bv.y; Bs[bK][bN + 2] = bv.z; Bs[bK][bN + 3] = bv.w;
        } else {
#pragma unroll
            for (int j = 0; j < 4; j++) {
                int n = n0 + bN + j;
                Bs[bK][bN + j] = (n < N) ? B[(long)(k0 + bK) * N + n] : 0.f;
            }
        }
        __syncthreads();
#pragma unroll
        for (int kk = 0; kk < 16; kk++) {
            float4 a4 = *(const float4*)&As[kk][ty * 4];
            float4 b4 = *(const float4*)&Bs[kk][tx * 4];
            float a[4] = {a4.x, a4.y, a4.z, a4.w};
            float bb[4] = {b4.x, b4.y, b4.z, b4.w};
#pragma unroll
            for (int ii = 0; ii < 4; ii++)
#pragma unroll
                for (int jj = 0; jj < 4; jj++)
                    acc[ii][jj] += a[ii] * bb[jj];
        }
        __syncthreads();
    }
#pragma unroll
    for (int ii = 0; ii < 4; ii++) {
        int m = m0 + ty * 4 + ii;
#pragma unroll
        for (int jj = 0; jj < 4; jj++) {
            int n = n0 + tx * 4 + jj;
            if (n < N) {
                float v = acc[ii][jj] + bias[n];
                if (!scatter) {
                    C[(long)m * N + n] = v;
                } else {
                    if (n < 6)       C[(long)m * 6 + n] = v;
                    else if (n < 30) C[49152 + (long)m * 24 + (n - 6)] = v;
                }
            }
        }
    }
}

// ---------------------------------------------------------------- bf16 MFMA GEMM (Bt = (N,K))
__global__ __launch_bounds__(256) void gemm_mfma_bt_kernel(
    const ushort* __restrict__ A, const ushort* __restrict__ Bt,
    const float* __restrict__ bias, float* __restrict__ Cf, ushort* __restrict__ Cb,
    int M, int N, int K, int relu)
{
    __shared__ ushort As[128 * 32];
    __shared__ ushort Bs[128 * 32];
    int t = threadIdx.x;
    int w = t >> 6, l = t & 63;
    int quad = l >> 4, lm = l & 15;
    int wm = w >> 1, wn = w & 1;
    long m0 = blockIdx.y * 128L;
    long n0 = blockIdx.x * 128L;
    int lr = t >> 2;
    int lk = (t & 3) * 8;
    f32x4 acc[4][4];
#pragma unroll
    for (int i = 0; i < 4; i++)
#pragma unroll
        for (int j = 0; j < 4; j++) acc[i][j] = (f32x4){0.f, 0.f, 0.f, 0.f};

    for (int k0 = 0; k0 < K; k0 += 32) {
        uint4 a0 = *(const uint4*)(A + (m0 + lr) * K + k0 + lk);
        uint4 a1 = *(const uint4*)(A + (m0 + 64 + lr) * K + k0 + lk);
        uint4 b0 = *(const uint4*)(Bt + (n0 + lr) * K + k0 + lk);
        uint4 b1 = *(const uint4*)(Bt + (n0 + 64 + lr) * K + k0 + lk);
        __syncthreads();
        *(uint4*)&As[lr * 32 + lk] = a0;
        *(uint4*)&As[(64 + lr) * 32 + lk] = a1;
        *(uint4*)&Bs[lr * 32 + lk] = b0;
        *(uint4*)&Bs[(64 + lr) * 32 + lk] = b1;
        __syncthreads();
        short8 af[4], bfr[4];
#pragma unroll
        for (int i = 0; i < 4; i++)
            af[i] = *(const short8*)&As[(wm * 64 + i * 16 + lm) * 32 + quad * 8];
#pragma unroll
        for (int j = 0; j < 4; j++)
            bfr[j] = *(const short8*)&Bs[(wn * 64 + j * 16 + lm) * 32 + quad * 8];
#pragma unroll
        for (int i = 0; i < 4; i++)
#pragma unroll
            for (int j = 0; j < 4; j++)
                acc[i][j] = __builtin_amdgcn_mfma_f32_16x16x32_bf16(af[i], bfr[j], acc[i][j], 0, 0, 0);
    }
#pragma unroll
    for (int i = 0; i < 4; i++) {
#pragma unroll
        for (int j = 0; j < 4; j++) {
            int n = (int)n0 + wn * 64 + j * 16 + lm;
            float bv = bias[n];
#pragma unroll
            for (int r = 0; r < 4; r++) {
                int m = (int)m0 + wm * 64 + i * 16 + quad * 4 + r;
                float v = acc[i][j][r] + bv;
                if (relu) v = fmaxf(v, 0.f);
                if (Cf) Cf[(long)m * N + n] = v;
                if (Cb) Cb[(long)m * N + n] = f2bf(v);
            }
        }
    }
}

// ---------------------------------------------------------------- nearest (both SN=512 and SN=128)
__global__ void nearest_both_kernel(const float* __restrict__ verts, int* __restrict__ n1,
                                    int* __restrict__ n2) {
    __shared__ float sx[512], sy[512], sz[512];
    int gb = blockIdx.x;
    int SN = (gb < 32) ? 512 : 128;
    int* out = (gb < 32) ? n1 : n2;
    int t = (gb & 31) * 256 + threadIdx.x;
    int b = t / VN;
    const float* vb = verts + (long)b * VN * 3;
    for (int j = threadIdx.x; j < SN; j += 256) {
        sx[j] = vb[j * 3]; sy[j] = vb[j * 3 + 1]; sz[j] = vb[j * 3 + 2];
    }
    __syncthreads();
    int i = t % VN;
    float px = vb[i * 3], py = vb[i * 3 + 1], pz = vb[i * 3 + 2];
    float best = 1e30f; int bi = 0;
    for (int j = 0; j < SN; j++) {
        float dx = sx[j] - px, dy = sy[j] - py, dz = sz[j] - pz;
        float dd = dx * dx + dy * dy + dz * dz;
        bool lt = dd < best;
        best = lt ? dd : best;
        bi = lt ? j : bi;
    }
    out[t] = bi;
}

// ---------------------------------------------------------------- fuse: bf16 GEMM input + fp32 feat output
__global__ void fuse_bf_kernel(const float* __restrict__ fm0, const float* __restrict__ fm1,
                               const float* __restrict__ fm2, const float* __restrict__ fm3,
                               const float* __restrict__ fm4, const unsigned* __restrict__ fg_enc,
                               const float* __restrict__ onehot,
                               const int* __restrict__ n1, const int* __restrict__ n2,
                               ushort* __restrict__ fuse_b, float* __restrict__ feat) {
    long i = blockIdx.x * 256L + threadIdx.x;
    if (i >= 8192L * 1824) return;
    int c = (int)(i % 1824);
    long row = i / 1824;
    int b = (int)(row / VN);
    float val = 0.f;
    if (c < 128)       val = fm0[row * 128 + c];
    else if (c < 256)  val = fm1[row * 128 + (c - 128)];
    else if (c < 512)  val = fm2[((long)b * 512 + n1[row]) * 256 + (c - 256)];
    else if (c < 768)  val = fm3[((long)b * 512 + n1[row]) * 256 + (c - 512)];
    else if (c < 1280) val = fm4[((long)b * 128 + n2[row]) * 512 + (c - 768)];
    else if (c < 1792) val = fdec(fg_enc[b * 512 + (c - 1280)]);
    else if (c < 1808) val = onehot[b * 16 + (c - 1792)];
    fuse_b[i] = f2bf(val);
    if (c < 1280)                   feat[row * 1296 + c] = val;
    else if (c >= 1792 && c < 1808) feat[row * 1296 + (c - 512)] = val;
}

// ---------------------------------------------------------------- launch

extern "C" void kernel_launch(void* const* d_in, const int* in_sizes, int n_in,
                              void* d_out, int out_size, void* d_ws, size_t ws_size,
                              hipStream_t stream) {
    const float* verts  = (const float*)d_in[0];
    const float* onehot = (const float*)d_in[1];
    const float* dir0 = (const float*)d_in[2];
    const float* w1 = (const float*)d_in[3];
    const float* b1 = (const float*)d_in[4];
    const float* dir1 = (const float*)d_in[5];
    const float* w2 = (const float*)d_in[6];
    const float* b2 = (const float*)d_in[7];
    const float* dir2 = (const float*)d_in[8];
    const float* w3 = (const float*)d_in[9];
    const float* b3 = (const float*)d_in[10];
    const float* dir3 = (const float*)d_in[11];
    const float* w4 = (const float*)d_in[12];
    const float* b4 = (const float*)d_in[13];
    const float* dir4 = (const float*)d_in[14];
    const float* g_bn1 = (const float*)d_in[15];
    const float* be_bn1 = (const float*)d_in[16];
    const float* g_bn2 = (const float*)d_in[17];
    const float* be_bn2 = (const float*)d_in[18];
    const float* g_bn3 = (const float*)d_in[19];
    const float* be_bn3 = (const float*)d_in[20];
    const float* wc1 = (const float*)d_in[21];
    const float* bc1 = (const float*)d_in[22];
    const float* wc2 = (const float*)d_in[23];
    const float* bc2 = (const float*)d_in[24];
    const float* wc3 = (const float*)d_in[25];
    const float* bc3 = (const float*)d_in[26];
    float* outf = (float*)d_out;

    float* wsf = (float*)d_ws;
    size_t off = 0;
    auto alloc = [&](size_t n) { float* p = wsf + off; off += (n + 15) & ~(size_t)15; return p; };

    float* sd0 = alloc(3 * 896);
    float* sd1 = alloc(3 * 896);
    float* sd2 = alloc(3 * 1792);
    float* sd3 = alloc(3 * 1792);
    float* sd4 = alloc(3 * 3584);
    float* wc3t = alloc(512L * 30);
    float* fm0 = alloc(8192L * 128);
    float* fm1 = alloc(8192L * 128);
    float* c1  = alloc(8192L * 128);
    float* fm2 = alloc(2048L * 256);
    float* c2  = alloc(2048L * 256);
    float* fm3 = alloc(2048L * 256);
    float* c3  = alloc(2048L * 256);
    float* fm4 = alloc(512L * 512);
    unsigned* fg_enc = (unsigned*)alloc(BSZ * 512);
    float* fbuf = alloc(8192L * 1024);
    float* h2 = alloc(8192L * 512);
    float* bnstat = alloc(512);
    float* pd  = alloc(KTOT);
    int* pi    = (int*)alloc(KTOT);
    int* nb   = (int*)alloc(8192L * KNB);
    int* nb1  = (int*)alloc(2048L * KNB);
    int* nb2  = (int*)alloc(512L * KNB);
    int* nbp1 = (int*)alloc(2048L * 4);
    int* nbp2 = (int*)alloc(512L * 4);
    int* n1   = (int*)alloc(8192);
    int* n2   = (int*)alloc(8192);
    ushort* fuse_b = (ushort*)alloc(8192L * 1824 / 2);
    ushort* h1b    = (ushort*)alloc(8192L * 512 / 2);
    ushort* wc1b   = (ushort*)alloc(512L * 1824 / 2);
    ushort* wc2b   = (ushort*)alloc(512L * 512 / 2);
    ushort* w1tb   = (ushort*)alloc(1024L * 128 / 2);
    ushort* w2tb   = (ushort*)alloc(2048L * 128 / 2);
    ushort* w3tb   = (ushort*)alloc(2048L * 256 / 2);
    ushort* w4tb   = (ushort*)alloc(4096L * 256 / 2);
    ushort* fm0b   = (ushort*)alloc(8192L * 128 / 2);
    ushort* fp1b   = (ushort*)alloc(2048L * 128 / 2);
    ushort* fm2b   = (ushort*)alloc(2048L * 256 / 2);
    ushort* fp2b   = (ushort*)alloc(512L * 256 / 2);

    auto nblk = [](long n, int b) { return (unsigned)((n + b - 1) / b); };

    // prep
    norm_dirs_all<<<35, 256, 0, stream>>>(dir0, dir1, dir2, dir3, dir4, sd0, sd1, sd2, sd3, sd4);
    transpose_kernel<<<nblk(30L * 512, 256), 256, 0, stream>>>(wc3, wc3t, 30, 512);
    f2b_pad_kernel<<<nblk(512L * 1824, 256), 256, 0, stream>>>(wc1, wc1b, 512, 1808, 1824);
    f2b_pad_kernel<<<nblk(512L * 512, 256), 256, 0, stream>>>(wc2, wc2b, 512, 512, 512);
    wt_f2b_all<<<7680, 256, 0, stream>>>(w1, w2, w3, w4, w1tb, w2tb, w3tb, w4tb);

    // knn graphs
    knn_part_uber<<<692, 256, 0, stream>>>(verts, pd, pi);
    knn_merge_uber<<<52, 256, 0, stream>>>(pd, pi, nb, nb1, nb2, nbp1, nbp2);

    // fm0
    conv_surface_kernel<<<BSZ * 2048, 128, 0, stream>>>(verts, nb, sd0, fm0, fm0b);

    // layer1 (M=8192, N=1024, K=128)
    gemm_mfma_bt_kernel<<<dim3(8, 64), 256, 0, stream>>>(fm0b, w1tb, b1, fbuf, nullptr, 8192, 1024, 128, 0);
    conv_act_kernel<<<BSZ * 2048, 128, 0, stream>>>(verts, nb, sd1, fbuf, c1, nullptr, 2048, 128);
    hipMemsetAsync(bnstat, 0, 2 * 128 * sizeof(float), stream);
    bn_stat_kernel<<<256, 256, 0, stream>>>(c1, bnstat, 8192, 128);
    bn_apply_relu_kernel<<<nblk(8192L * 128, 256), 256, 0, stream>>>(c1, bnstat, g_bn1, be_bn1, fm1, nullptr, 8192, 128);

    // pool1 -> bf16
    pool_b_kernel<<<nblk(BSZ * 512L * 128, 256), 256, 0, stream>>>(fm1, nbp1, fp1b, 2048, 512, 128);

    // layer2 (M=2048, N=2048, K=128)
    gemm_mfma_bt_kernel<<<dim3(16, 16), 256, 0, stream>>>(fp1b, w2tb, b2, fbuf, nullptr, 2048, 2048, 128, 0);
    conv_act_kernel<<<BSZ * 512, 256, 0, stream>>>(verts, nb1, sd2, fbuf, c2, nullptr, 512, 256);
    hipMemsetAsync(bnstat, 0, 2 * 256 * sizeof(float), stream);
    bn_stat_kernel<<<256, 256, 0, stream>>>(c2, bnstat, 2048, 256);
    bn_apply_relu_kernel<<<nblk(2048L * 256, 256), 256, 0, stream>>>(c2, bnstat, g_bn2, be_bn2, fm2, fm2b, 2048, 256);

    // layer3 (M=2048, N=2048, K=256)
    gemm_mfma_bt_kernel<<<dim3(16, 16), 256, 0, stream>>>(fm2b, w3tb, b3, fbuf, nullptr, 2048, 2048, 256, 0);
    conv_act_kernel<<<BSZ * 512, 256, 0, stream>>>(verts, nb1, sd3, fbuf, c3, nullptr, 512, 256);
    hipMemsetAsync(bnstat, 0, 2 * 256 * sizeof(float), stream);
    bn_stat_kernel<<<256, 256, 0, stream>>>(c3, bnstat, 2048, 256);
    bn_apply_relu_kernel<<<nblk(2048L * 256, 256), 256, 0, stream>>>(c3, bnstat, g_bn3, be_bn3, fm3, nullptr, 2048, 256);

    // pool2 -> bf16
    pool_b_kernel<<<nblk(BSZ * 128L * 256, 256), 256, 0, stream>>>(fm3, nbp2, fp2b, 512, 128, 256);

    // layer4 (M=512, N=4096, K=256); conv_act also reduces fg via atomicMax
    gemm_mfma_bt_kernel<<<dim3(32, 4), 256, 0, stream>>>(fp2b, w4tb, b4, fbuf, nullptr, 512, 4096, 256, 0);
    hipMemsetAsync(fg_enc, 0, BSZ * 512 * sizeof(unsigned), stream);
    conv_act_kernel<<<BSZ * 128, 512, 0, stream>>>(verts, nb2, sd4, fbuf, fm4, fg_enc, 128, 512);

    // upsample indices
    nearest_both_kernel<<<64, 256, 0, stream>>>(verts, n1, n2);

    // fuse -> bf16 GEMM input + fp32 feat (direct to d_out)
    fuse_bf_kernel<<<nblk(8192L * 1824, 256), 256, 0, stream>>>(fm0, fm1, fm2, fm3, fm4, fg_enc, onehot,
                                                                n1, n2, fuse_b, outf + 245760);

    // MLP head (wc3 GEMM scatters seg/vecs directly into d_out)
    gemm_mfma_bt_kernel<<<dim3(4, 64), 256, 0, stream>>>(fuse_b, wc1b, bc1, nullptr, h1b, 8192, 512, 1824, 1);
    gemm_mfma_bt_kernel<<<dim3(4, 64), 256, 0, stream>>>(h1b, wc2b, bc2, h2, nullptr, 8192, 512, 512, 1);
    gemm_kernel<<<dim3(1, 128), 256, 0, stream>>>(h2, wc3t, bc3, outf, 8192, 512, 30, 1);
}